// Round 4
// baseline (785.387 us; speedup 1.0000x reference)
//
#include <hip/hip_runtime.h>
#include <cmath>

#define S_ 1024
#define B_ 8
#define H_ 512
#define S2_ 1022
#define M_ (B_*S2_)     // 8176
#define PAD_ 8192
#define VTS_ ((size_t)8*8*64*1024)   // VT per-branch stride (4194304 shorts)

typedef __attribute__((ext_vector_type(8))) short bf16x8;
typedef __attribute__((ext_vector_type(4))) float f32x4;
typedef __attribute__((ext_vector_type(4))) unsigned int u32x4;
typedef __attribute__((ext_vector_type(2))) unsigned int u32x2;

__device__ __forceinline__ unsigned short f2bf(float f){
  unsigned int u = __float_as_uint(f);
  return (unsigned short)((u + 0x7fffu + ((u>>16)&1u)) >> 16);
}
__device__ __forceinline__ float bf2f(unsigned short u){
  return __uint_as_float((unsigned int)u << 16);
}
// tanh-approx gelu: x*sigmoid(2*(c1 x + c2 x^3)); |err vs erf-gelu| < ~3e-4
__device__ __forceinline__ float fgelu(float x){
  float u = x * (0.7978845608f + 0.0356774081f * x * x);
  return x / (1.f + __expf(-2.f * u));
}
// raw 2^x (v_exp_f32 is natively base-2)
__device__ __forceinline__ float fexp2(float x){
  float r; asm("v_exp_f32 %0, %1" : "=v"(r) : "v"(x)); return r;
}
// hardware packed f32->bf16 (RNE), lo -> bits[15:0], hi -> bits[31:16]
__device__ __forceinline__ unsigned int cvtpk(float lo, float hi){
  unsigned int r; asm("v_cvt_pk_bf16_f32 %0, %1, %2" : "=v"(r) : "v"(lo), "v"(hi)); return r;
}

__device__ __forceinline__ void glds16(const void* g, void* l){
  __builtin_amdgcn_global_load_lds((const __attribute__((address_space(1))) unsigned int*)g,
                                   (__attribute__((address_space(3))) unsigned int*)l, 16, 0, 0);
}

// ---------------------------------------------------------------- prep: X = [f[:-2], bk[2:]] bf16 (M_ x 1024)
__global__ __launch_bounds__(256) void lma_prep_x(const float* __restrict__ hidden,
                                                  unsigned short* __restrict__ Xb){
  int m = blockIdx.x; int dq = threadIdx.x * 4;
  int b = m / S2_, s = m - b * S2_;
  int srow = (dq < 512) ? s : (s + 2);
  const float* src = hidden + ((size_t)srow * B_ + b) * 1024 + dq;
  f32x4 v = *(const f32x4*)src;
  union { u32x2 u; unsigned short s4[4]; } pk;
  #pragma unroll
  for (int j = 0; j < 4; j++) pk.s4[j] = f2bf(v[j]);
  *(u32x2*)&Xb[(size_t)m * 1024 + dq] = pk.u;
}

// ---------------------------------------------------------------- batched weight transpose+cast
struct TPack {
  const float* src[14];
  unsigned short* dst[14];
  int K[14];
  int N[14];
};
__global__ __launch_bounds__(256) void lma_transpose_all(TPack p){
  int idx = blockIdx.z;
  int K = p.K[idx], N = p.N[idx];
  int kb = blockIdx.x * 32, nb = blockIdx.y * 32;
  if (kb >= K || nb >= N) return;
  const float* W = p.src[idx];
  unsigned short* WT = p.dst[idx];
  __shared__ float t[32][33];
  int tx = threadIdx.x & 31, ty = threadIdx.x >> 5;
  #pragma unroll
  for (int i = ty; i < 32; i += 8) t[i][tx] = W[(size_t)(kb + i) * N + nb + tx];
  __syncthreads();
  #pragma unroll
  for (int i = ty; i < 32; i += 8) WT[(size_t)(nb + i) * K + kb + tx] = f2bf(t[tx][i]);
}

// ---------------------------------------------------------------- concat K/V biases
__global__ __launch_bounds__(256) void lma_biascat(const float* __restrict__ fk, const float* __restrict__ fv,
                                                   const float* __restrict__ bk, const float* __restrict__ bv,
                                                   float* __restrict__ out){
  int i = blockIdx.x * 256 + threadIdx.x;     // 0..2047
  int fb = i >> 10, col = i & 1023;
  const float* s = (col < 512) ? (fb ? bk : fk) : (fb ? bv : fv);
  out[i] = s[col & 511];
}

// ---------------------------------------------------------------- V (in KV2, cols 512..1023) -> VT2[fb][b][h][d][s pad 1024]
// Pad cols s in [S2_,1024) ZEROED (aliased buffer may hold bf16-NaN bit patterns).
__global__ __launch_bounds__(256) void lma_vt2(const unsigned short* __restrict__ KV2,
                                               unsigned short* __restrict__ VT2){
  __shared__ unsigned short t[32][34];
  int s0 = blockIdx.x * 32, c0 = blockIdx.y * 32;
  int z = blockIdx.z, fb = z >> 3, b = z & 7;
  const unsigned short* V = KV2 + (size_t)fb * PAD_ * 1024 + 512;
  unsigned short* VT = VT2 + (size_t)fb * VTS_;
  int tx = threadIdx.x & 31, ty = threadIdx.x >> 5;
  #pragma unroll
  for (int i = ty; i < 32; i += 8){
    int s = s0 + i; if (s > S2_-1) s = S2_-1;
    t[i][tx] = V[((size_t)b * S2_ + s) * 1024 + c0 + tx];
  }
  __syncthreads();
  int s = s0 + tx;
  #pragma unroll
  for (int i = ty; i < 32; i += 8){
    int c = c0 + i, h = c >> 6, d = c & 63;
    VT[(((size_t)b * 8 + h) * 64 + d) * 1024 + s] = (s < S2_) ? t[tx][i] : (unsigned short)0;
  }
}

// ---------------------------------------------------------------- branch-combined GEMM, flat grid + XCD-reuse swizzle
// id: mt = id % nmt (m-tile FASTEST; nmt always multiple of 8 => all n-tile
// readers of A-tile mt have id%8 = mt%8 -> same XCD -> A fetched once/XCD).
// rows < 8192 use (Bt0,bias0), rows >= 8192 use (Bt1,bias1).
// amap: 0 direct (clamp M-1) | 1 row=(r&8191) clamp M_-1 | 2 like 1 + +512 col for branch 1
// modes: 0 bf16 bias | 1 bf16 bias*0.125*log2e (Q pre-scale, exp2-domain softmax)
//        | 2 bf16 bias+gelu(tanh) | 3 f32 bias | 4 f32 bias row-remap (s*B+b)
__global__ __launch_bounds__(256) void lma_gemm2(
    const unsigned short* __restrict__ A, int lda,
    const unsigned short* __restrict__ Bt0, const unsigned short* __restrict__ Bt1,
    const float* __restrict__ bias0, const float* __restrict__ bias1,
    void* __restrict__ Cout, int ldc,
    int M, int N, int K, int mode, int amap, int nmt)
{
  __shared__ unsigned short Al[128*32];
  __shared__ unsigned short Bl[128*32];
  const int tid = threadIdx.x;
  const int w = tid >> 6, lane = tid & 63, quad = lane >> 4, l16 = lane & 15;
  const int mt = blockIdx.x % nmt, nt = blockIdx.x / nmt;
  const int m0 = mt * 128, n0 = nt * 128;
  const int brch = m0 >> 13;
  const unsigned short* Bt = brch ? Bt1 : Bt0;
  const float* bias = brch ? bias1 : bias0;
  const int coloff = (amap == 2 && brch) ? 512 : 0;
  const int wm = (w >> 1) * 64, wn = (w & 1) * 64;

  f32x4 acc[4][4];
  #pragma unroll
  for (int i = 0; i < 4; i++)
    #pragma unroll
    for (int f = 0; f < 4; f++) acc[i][f] = f32x4{0.f,0.f,0.f,0.f};

  const int srow = lane >> 2;
  const int spc  = (lane & 3) * 8;

  for (int k0 = 0; k0 < K; k0 += 32) {
    #pragma unroll
    for (int c = 0; c < 2; c++) {
      int ra = w*32 + c*16 + srow;
      int ga = m0 + ra;
      int ar;
      if (amap == 0) { ar = (ga > M-1) ? (M-1) : ga; }
      else { ar = ga & (PAD_-1); if (ar > M_-1) ar = M_-1; }
      glds16(A + (size_t)ar * lda + coloff + k0 + spc, &Al[(w*32 + c*16) * 32]);
      int gb = n0 + ra; if (gb > N-1) gb = N-1;
      glds16(Bt + (size_t)gb * K + k0 + spc, &Bl[(w*32 + c*16) * 32]);
    }
    __syncthreads();
    bf16x8 af[4], bfr[4];
    #pragma unroll
    for (int i = 0; i < 4; i++) af[i]  = *(const bf16x8*)&Al[(wm + i*16 + l16)*32 + quad*8];
    #pragma unroll
    for (int f = 0; f < 4; f++) bfr[f] = *(const bf16x8*)&Bl[(wn + f*16 + l16)*32 + quad*8];
    #pragma unroll
    for (int i = 0; i < 4; i++)
      #pragma unroll
      for (int f = 0; f < 4; f++)
        acc[i][f] = __builtin_amdgcn_mfma_f32_16x16x32_bf16(af[i], bfr[f], acc[i][f], 0, 0, 0);
    __syncthreads();
  }

  #pragma unroll
  for (int f = 0; f < 4; f++) {
    int col = n0 + wn + f*16 + l16;
    float bv = bias ? bias[col] : 0.f;
    #pragma unroll
    for (int i = 0; i < 4; i++) {
      #pragma unroll
      for (int r = 0; r < 4; r++) {
        int row = m0 + wm + i*16 + quad*4 + r;
        if (row < M) {
          float v = acc[i][f][r] + bv;
          if (mode == 2) v = fgelu(v);
          else if (mode == 1) v *= 0.18033688011112042f;   // 0.125 * log2(e)
          if (mode <= 2) ((unsigned short*)Cout)[(size_t)row * ldc + col] = f2bf(v);
          else if (mode == 3) ((float*)Cout)[(size_t)row * ldc + col] = v;
          else {
            int sr = row % S2_, bb2 = row / S2_;
            ((float*)Cout)[((size_t)sr * B_ + bb2) * ldc + col] = v;
          }
        }
      }
    }
  }
}

// ---------------------------------------------------------------- block reduction helper
__device__ __forceinline__ void lma_red2(float& s, float& sq){
  __shared__ float red[16];
  #pragma unroll
  for (int msk = 1; msk < 64; msk <<= 1){ s += __shfl_xor(s, msk); sq += __shfl_xor(sq, msk); }
  int w = threadIdx.x >> 6;
  if ((threadIdx.x & 63) == 0){ red[w] = s; red[8 + w] = sq; }
  __syncthreads();
  s  = red[0] + red[1] + red[2] + red[3];
  sq = red[8] + red[9] + red[10] + red[11];
}

// ---------------------------------------------------------------- generic LN (f32 in, bf16 or f32 out)
__global__ __launch_bounds__(256) void lma_ln(const float* __restrict__ in,
                                              const float* __restrict__ g, const float* __restrict__ bb,
                                              int D, unsigned short* __restrict__ obf, float* __restrict__ of32){
  int row = blockIdx.x, t = threadIdx.x;
  const float* x = in + (size_t)row * D;
  float s = 0.f, sq = 0.f;
  for (int d = t; d < D; d += 256){ float v = x[d]; s += v; sq += v * v; }
  lma_red2(s, sq);
  float mean = s / D;
  float var = sq / D - mean * mean;
  float rstd = rsqrtf(fmaxf(var, 0.f) + 1e-12f);
  if (obf) {
    for (int d = t; d < D; d += 256) obf[(size_t)row * D + d] = f2bf((x[d] - mean) * rstd * g[d] + bb[d]);
  } else {
    for (int d = t; d < D; d += 256) of32[(size_t)row * D + d] = (x[d] - mean) * rstd * g[d] + bb[d];
  }
}

// ---------------------------------------------------------------- branch-combined LN over T12b (bf16, D=512) -> LQ2 bf16
__global__ __launch_bounds__(256) void lma_ln2(const unsigned short* __restrict__ T12b,
                                               const float* __restrict__ fg, const float* __restrict__ fbb,
                                               const float* __restrict__ bg, const float* __restrict__ bbb,
                                               unsigned short* __restrict__ LQ2){
  int m = blockIdx.x, t = threadIdx.x;           // 0..2*M_-1
  int fb = (m >= M_);
  int idx = m - fb * M_;
  const float* g = fb ? bg : fg;
  const float* bb = fb ? bbb : fbb;
  const unsigned short* x = T12b + ((size_t)fb * PAD_ + idx) * 512;
  unsigned short* o = LQ2 + ((size_t)fb * PAD_ + idx) * 512;
  float v0 = bf2f(x[t]), v1 = bf2f(x[t + 256]);
  float s = v0 + v1, sq = v0*v0 + v1*v1;
  lma_red2(s, sq);
  float mean = s / 512.f;
  float var = sq / 512.f - mean * mean;
  float rstd = rsqrtf(fmaxf(var, 0.f) + 1e-12f);
  o[t]       = f2bf((v0 - mean) * rstd * g[t]       + bb[t]);
  o[t + 256] = f2bf((v1 - mean) * rstd * g[t + 256] + bb[t + 256]);
}

// ---------------------------------------------------------------- attn LN: LN(residual(hidden)+[pf,pb](bf16)) -> bf16 (M_ x 1024)
__global__ __launch_bounds__(256) void lma_attn_ln(const unsigned short* __restrict__ pf,
                                                   const unsigned short* __restrict__ pb,
                                                   const float* __restrict__ hidden,
                                                   const float* __restrict__ g, const float* __restrict__ bb,
                                                   unsigned short* __restrict__ out){
  int m = blockIdx.x, t = threadIdx.x;
  int b = m / S2_, s = m - b * S2_;
  const float* hf = hidden + ((size_t)s       * B_ + b) * 1024;
  const float* hb = hidden + ((size_t)(s + 2) * B_ + b) * 1024;
  float v[4]; float sum = 0.f, sq = 0.f;
  #pragma unroll
  for (int j = 0; j < 4; j++){
    int d = t + j * 256;
    float x = (d < 512) ? (bf2f(pf[(size_t)m * 512 + d]) + hf[d])
                        : (bf2f(pb[(size_t)m * 512 + (d - 512)]) + hb[d]);
    v[j] = x; sum += x; sq += x * x;
  }
  lma_red2(sum, sq);
  float mean = sum / 1024.f;
  float var = sq / 1024.f - mean * mean;
  float rstd = rsqrtf(fmaxf(var, 0.f) + 1e-12f);
  #pragma unroll
  for (int j = 0; j < 4; j++){
    int d = t + j * 256;
    out[(size_t)m * 1024 + d] = f2bf((v[j] - mean) * rstd * g[d] + bb[d]);
  }
}

// ---------------------------------------------------------------- combined flash attention v8
// Fully wave-independent: NO K/V LDS staging, NO barriers. Per (b,h) the K and V
// slices are 128KB each and the per-XCD working set (i%8 = h clustering) is
// ~4MB ~ L2, so staging through LDS was pure overhead (guide m169 pattern); the
// barrier lockstep it required was the real cost (v7's counted-vmcnt pipeline
// was neutral: MfmaUtil 8.2->8.2). Each wave owns 16 q rows, loads K/V fragments
// straight from global into the MFMA register layout, and runs its own k-range
// (khi = q0+15, not block-wide q0wg+63 -> ~20% fewer fwd tiles). vf loads are
// issued right after QK so L2 latency hides under the softmax chain; kf dies at
// QK -> peak VGPR ~90 (cap 128 via (256,4); v5's spill disaster was the (256,8)
// 64-VGPR cap, not this structure). P reshuffle stays in per-wave 2KB LDS
// (XOR-swizzled, no sync needed). f2bf P-pack -> v_cvt_pk_bf16_f32 (48->8 insts).
// exp2-domain softmax, defer-max, interior-tile mask skip, setprio retained.
__global__ __launch_bounds__(256, 4) void lma_attn8(const unsigned short* __restrict__ Q2,
                                                    const unsigned short* __restrict__ KV2,
                                                    const unsigned short* __restrict__ VT2,
                                                    unsigned short* __restrict__ CT2,
                                                    const int* __restrict__ lens){
  __shared__ __align__(16) unsigned short Pl[4][16*64];   // per-wave 2KB, wave-private

  const int tid = threadIdx.x;
  const int w = tid >> 6, lane = tid & 63, quad = lane >> 4, l16 = lane & 15;
  const int id = blockIdx.x;                 // 1024 blocks
  // XCD clustering heuristic: id%8 = h -> each XCD sees one h for all b:
  // K/V working set per XCD = 8b x 2branch x 256KB = 4MB ~ its L2.
  const int h = id & 7, qtB = (id >> 3) & 15, b = id >> 7;
  const int L2 = lens[b] - 2;
  const int q0 = qtB * 64 + w * 16;          // this wave's 16 q rows
  const int qg = q0 + l16;
  const int qload = (qg > S2_-1) ? (S2_-1) : qg;

  const size_t qbase  = ((size_t)b * S2_) * 512  + h * 64;
  const size_t kbase  = ((size_t)b * S2_) * 1024 + h * 64;
  const size_t vtbase = ((size_t)(b * 8 + h) * 64) * 1024;
  char* Pb = (char*)&Pl[w][0];
  const int x7s = (l16 & 7) << 4;

  for (int fb = 0; fb < 2; fb++) {
    const int backward = fb;
    const unsigned short* Q  = Q2  + (size_t)fb * PAD_ * 512;
    const unsigned short* Kx = KV2 + (size_t)fb * PAD_ * 1024;
    const unsigned short* VT = VT2 + (size_t)fb * VTS_;
    unsigned short* CTX      = CT2 + (size_t)fb * PAD_ * 512;

    bf16x8 qf[2];
    {
      const unsigned short* qp = Q + qbase + (size_t)qload * 512 + quad * 8;
      qf[0] = *(const bf16x8*)(qp);
      qf[1] = *(const bf16x8*)(qp + 32);
    }

    float mi = -3e38f, li = 0.f;
    f32x4 ot[4];
    #pragma unroll
    for (int f = 0; f < 4; f++) ot[f] = f32x4{0.f,0.f,0.f,0.f};

    int klo = 0, khi = S2_ - 1;
    if (q0 + 15 < L2) {
      if (!backward) khi = q0 + 15;
      else { klo = q0 & ~63; khi = L2 - 1; }
    }

    for (int kt0 = klo; kt0 <= khi; kt0 += 64) {
      // K fragments direct from global (L2-resident): lane = K[kr][quad*8..]
      bf16x8 kf[4][2];
      #pragma unroll
      for (int sub = 0; sub < 4; sub++) {
        int kr = kt0 + sub*16 + l16; if (kr > S2_-1) kr = S2_-1;
        const unsigned short* kp = Kx + kbase + (size_t)kr * 1024 + quad * 8;
        kf[sub][0] = *(const bf16x8*)(kp);
        kf[sub][1] = *(const bf16x8*)(kp + 32);
      }

      f32x4 st[4];
      __builtin_amdgcn_s_setprio(1);
      #pragma unroll
      for (int sub = 0; sub < 4; sub++) {
        f32x4 s = f32x4{0.f,0.f,0.f,0.f};
        s = __builtin_amdgcn_mfma_f32_16x16x32_bf16(kf[sub][0], qf[0], s, 0, 0, 0);
        s = __builtin_amdgcn_mfma_f32_16x16x32_bf16(kf[sub][1], qf[1], s, 0, 0, 0);
        st[sub] = s;
      }
      __builtin_amdgcn_s_setprio(0);

      // V fragments issued now; latency hides under softmax (kf regs just died)
      bf16x8 vf[4][2];
      #pragma unroll
      for (int f = 0; f < 4; f++) {
        const unsigned short* vp = VT + vtbase + (size_t)(f*16 + l16) * 1024 + kt0 + quad * 8;
        vf[f][0] = *(const bf16x8*)(vp);
        vf[f][1] = *(const bf16x8*)(vp + 32);
      }

      // interior-tile skip: wave-uniform "every (lane,r) passes the mask"
      {
        bool tail = (kt0 + 63 > S2_ - 1);
        bool full;
        if (!backward) full = !tail && ((kt0 + 63 <= q0) || (q0 >= L2));
        else           full = !tail && ((q0 >= L2) || ((kt0 >= q0 + 15) && (kt0 + 63 < L2)));
        if (!full) {
          #pragma unroll
          for (int sub = 0; sub < 4; sub++) {
            #pragma unroll
            for (int r = 0; r < 4; r++) {
              int kg = kt0 + sub*16 + quad*4 + r;
              bool ok;
              if (!backward) ok = (kg < S2_) && ((qg >= L2) || (kg <= qg));
              else           ok = (kg < S2_) && ((qg >= L2) || ((kg >= qg) && (kg < L2)));
              if (!ok) st[sub][r] = -3e38f;
            }
          }
        }
      }

      float mx = -3e38f;
      #pragma unroll
      for (int sub = 0; sub < 4; sub++)
        #pragma unroll
        for (int r = 0; r < 4; r++) mx = fmaxf(mx, st[sub][r]);
      mx = fmaxf(mx, __shfl_xor(mx, 16));
      mx = fmaxf(mx, __shfl_xor(mx, 32));

      // defer-max (T13): only rescale when some row's max grew past THR (log2 units)
      if (__any(mx > mi + 11.f)) {
        float mn = fmaxf(mi, mx);
        float al = fexp2(mi - mn);
        li *= al;
        #pragma unroll
        for (int f = 0; f < 4; f++)
          #pragma unroll
          for (int r = 0; r < 4; r++) ot[f][r] *= al;
        mi = mn;
      }

      float rs = 0.f;
      #pragma unroll
      for (int sub = 0; sub < 4; sub++)
        #pragma unroll
        for (int r = 0; r < 4; r++) {
          float p = fexp2(st[sub][r] - mi);
          st[sub][r] = p; rs += p;
        }
      rs += __shfl_xor(rs, 16);
      rs += __shfl_xor(rs, 32);
      li += rs;

      // P round-trip through XOR-swizzled per-wave LDS (bank-balanced, no sync)
      #pragma unroll
      for (int sub = 0; sub < 4; sub++) {
        u32x2 pk2;
        pk2[0] = cvtpk(st[sub][0], st[sub][1]);
        pk2[1] = cvtpk(st[sub][2], st[sub][3]);
        *(u32x2*)(Pb + (l16*128 + ((sub*32 + quad*8) ^ x7s))) = pk2;
      }
      bf16x8 pfr0 = *(const bf16x8*)(Pb + (l16*128 + (( 0 + quad*16) ^ x7s)));
      bf16x8 pfr1 = *(const bf16x8*)(Pb + (l16*128 + ((64 + quad*16) ^ x7s)));

      __builtin_amdgcn_s_setprio(1);
      #pragma unroll
      for (int f = 0; f < 4; f++) {
        ot[f] = __builtin_amdgcn_mfma_f32_16x16x32_bf16(vf[f][0], pfr0, ot[f], 0, 0, 0);
        ot[f] = __builtin_amdgcn_mfma_f32_16x16x32_bf16(vf[f][1], pfr1, ot[f], 0, 0, 0);
      }
      __builtin_amdgcn_s_setprio(0);
    }

    if (qg < S2_) {
      float rcp = 1.f / li;
      #pragma unroll
      for (int f = 0; f < 4; f++) {
        ushort4 pk;
        pk.x = f2bf(ot[f][0] * rcp); pk.y = f2bf(ot[f][1] * rcp);
        pk.z = f2bf(ot[f][2] * rcp); pk.w = f2bf(ot[f][3] * rcp);
        *(ushort4*)&CTX[qbase + (size_t)qg * 512 + f*16 + quad*4] = pk;
      }
    }
  }
}

// ----------------------------------------------------------------
extern "C" void kernel_launch(void* const* d_in, const int* in_sizes, int n_in,
                              void* d_out, int out_size, void* d_ws, size_t ws_size,
                              hipStream_t stream)
{
  const float* hidden = (const float*)d_in[0];
  const int*   lens   = (const int*)d_in[1];
  const float* fw[14]; for (int i = 0; i < 14; i++) fw[i] = (const float*)d_in[2 + i];
  const float* bw[14]; for (int i = 0; i < 14; i++) bw[i] = (const float*)d_in[16 + i];
  const float* attn_g = (const float*)d_in[30];
  const float* attn_b = (const float*)d_in[31];
  const float* o_w1 = (const float*)d_in[32];
  const float* o_b1 = (const float*)d_in[33];
  const float* o_w2 = (const float*)d_in[34];
  const float* o_b2 = (const float*)d_in[35];
  const float* o_lng = (const float*)d_in[36];
  const float* o_lnb = (const float*)d_in[37];

  char* ws = (char*)d_ws;
  size_t off = 0;
  auto alloc = [&](size_t bytes)->char* {
    off = (off + 255) & ~(size_t)255;
    char* p = ws + off; off += bytes; return p;
  };

  unsigned short* fw1t = (unsigned short*)alloc((size_t)1024*1024*2);
  unsigned short* fw2t = (unsigned short*)alloc((size_t)512*1024*2);
  unsigned short* fqt  = (unsigned short*)alloc((size_t)512*512*2);
  unsigned short* fkvt = (unsigned short*)alloc((size_t)1024*512*2);  // [K(512 rows); V(512 rows)]
  unsigned short* fot  = (unsigned short*)alloc((size_t)512*512*2);
  unsigned short* bw1t = (unsigned short*)alloc((size_t)1024*1024*2);
  unsigned short* bw2t = (unsigned short*)alloc((size_t)512*1024*2);
  unsigned short* bqt  = (unsigned short*)alloc((size_t)512*512*2);
  unsigned short* bkvt = (unsigned short*)alloc((size_t)1024*512*2);
  unsigned short* bot  = (unsigned short*)alloc((size_t)512*512*2);
  unsigned short* ow1t = (unsigned short*)alloc((size_t)1024*1024*2);
  unsigned short* ow2t = (unsigned short*)alloc((size_t)1024*1024*2);
  float*          biasKV = (float*)alloc(2048*4);

  unsigned short* Xb   = (unsigned short*)alloc((size_t)M_*1024*2);
  unsigned short* big1 = (unsigned short*)alloc((size_t)2*PAD_*1024*2);
  float*          big2 = (float*)alloc((size_t)2*PAD_*512*4);
  unsigned short* LQCT = (unsigned short*)alloc((size_t)2*PAD_*512*2);
  unsigned short* Q2   = (unsigned short*)alloc((size_t)2*PAD_*512*2);

  unsigned short* H12 = big1, *KV2 = big1, *H1o = big1;
  // big2 partitions: [0 .. 2*VTS_) = T12b (bf16) then VT2 (bf16);
  //                  [2*VTS_ .. 4*VTS_) = P2b (bf16 out-proj). Exactly fills big2.
  unsigned short* T12b = (unsigned short*)big2;
  unsigned short* VT2  = (unsigned short*)big2;
  unsigned short* P2b  = (unsigned short*)big2 + 2*VTS_;
  unsigned short* LQ2 = LQCT, *CT2 = LQCT;

  lma_prep_x<<<M_, 256, 0, stream>>>(hidden, Xb);

  {
    TPack tp;
    const float* srcs[14] = { fw[0], fw[2], fw[6], fw[8], fw[10], fw[12],
                              bw[0], bw[2], bw[6], bw[8], bw[10], bw[12],
                              o_w1, o_w2 };
    unsigned short* dsts[14] = { fw1t, fw2t, fqt, fkvt, fkvt + (size_t)512*512, fot,
                                 bw1t, bw2t, bqt, bkvt, bkvt + (size_t)512*512, bot,
                                 ow1t, ow2t };
    int Ks[14] = {1024,1024,512,512,512,512, 1024,1024,512,512,512,512, 1024,1024};
    int Ns[14] = {1024, 512,512,512,512,512, 1024, 512,512,512,512,512, 1024,1024};
    for (int i = 0; i < 14; i++){ tp.src[i]=srcs[i]; tp.dst[i]=dsts[i]; tp.K[i]=Ks[i]; tp.N[i]=Ns[i]; }
    lma_transpose_all<<<dim3(32, 32, 14), 256, 0, stream>>>(tp);
  }
  lma_biascat<<<8, 256, 0, stream>>>(fw[9], fw[11], bw[9], bw[11], biasKV);

  auto G = [&](const unsigned short* A, int lda,
               const unsigned short* B0, const unsigned short* B1,
               const float* b0, const float* b1,
               void* C, int ldc, int M, int N, int K, int mode, int amap){
    int nmt = (M + 127) / 128;
    lma_gemm2<<<dim3(nmt * (N/128)), 256, 0, stream>>>(A, lda, B0, B1, b0, b1, C, ldc, M, N, K, mode, amap, nmt);
  };

  // both-branch FFN + LN + projections (rows<8192 = forward, >=8192 = backward)
  G(Xb, 1024, fw1t, bw1t, fw[1], bw[1], H12, 1024, 2*PAD_, 1024, 1024, 2, 1);  // FFN1+gelu
  G(H12, 1024, fw2t, bw2t, fw[3], bw[3], T12b, 512, 2*PAD_, 512, 1024, 0, 0);  // FFN2 -> bf16
  lma_ln2<<<2*M_, 256, 0, stream>>>(T12b, fw[4], fw[5], bw[4], bw[5], LQ2);
  G(LQ2, 512, fqt, bqt, fw[7], bw[7], Q2, 512, 2*PAD_, 512, 512, 1, 0);        // Q (x0.125*log2e)
  G(Xb, 1024, fkvt, bkvt, biasKV, biasKV + 1024, KV2, 1024, 2*PAD_, 1024, 512, 0, 2); // K|V
  lma_vt2<<<dim3(32, 16, 16), 256, 0, stream>>>(KV2, VT2);

  lma_attn8<<<dim3(1024), 256, 0, stream>>>(Q2, KV2, VT2, CT2, lens);

  G(CT2, 512, fot, bot, fw[13], bw[13], P2b, 512, 2*PAD_, 512, 512, 0, 0);     // out proj -> bf16

  lma_attn_ln<<<M_, 256, 0, stream>>>(P2b, P2b + (size_t)PAD_*512, hidden, attn_g, attn_b, Xb);

  G(Xb, 1024, ow1t, ow1t, o_b1, o_b1, H1o, 1024, M_, 1024, 1024, 2, 0);        // out FFN1+gelu
  G(H1o, 1024, ow2t, ow2t, o_b2, o_b2, (float*)d_out, 1024, M_, 1024, 1024, 4, 0); // out FFN2 -> d_out (remapped)
  lma_ln<<<M_, 256, 0, stream>>>((float*)d_out, o_lng, o_lnb, 1024, nullptr, (float*)d_out);
}

// Round 5
// 654.527 us; speedup vs baseline: 1.1999x; 1.1999x over previous
//
#include <hip/hip_runtime.h>
#include <cmath>

#define S_ 1024
#define B_ 8
#define H_ 512
#define S2_ 1022
#define M_ (B_*S2_)     // 8176
#define PAD_ 8192
#define VTS_ ((size_t)8*8*64*1024)   // VT per-branch stride (4194304 shorts)

typedef __attribute__((ext_vector_type(8))) short bf16x8;
typedef __attribute__((ext_vector_type(4))) float f32x4;
typedef __attribute__((ext_vector_type(4))) unsigned int u32x4;
typedef __attribute__((ext_vector_type(2))) unsigned int u32x2;

__device__ __forceinline__ unsigned short f2bf(float f){
  unsigned int u = __float_as_uint(f);
  return (unsigned short)((u + 0x7fffu + ((u>>16)&1u)) >> 16);
}
__device__ __forceinline__ float bf2f(unsigned short u){
  return __uint_as_float((unsigned int)u << 16);
}
// tanh-approx gelu: x*sigmoid(2*(c1 x + c2 x^3)); |err vs erf-gelu| < ~3e-4
__device__ __forceinline__ float fgelu(float x){
  float u = x * (0.7978845608f + 0.0356774081f * x * x);
  return x / (1.f + __expf(-2.f * u));
}
// raw 2^x (v_exp_f32 is natively base-2)
__device__ __forceinline__ float fexp2(float x){
  float r; asm("v_exp_f32 %0, %1" : "=v"(r) : "v"(x)); return r;
}
// hardware packed f32->bf16 (RNE), lo -> bits[15:0], hi -> bits[31:16]
__device__ __forceinline__ unsigned int cvtpk(float lo, float hi){
  unsigned int r; asm("v_cvt_pk_bf16_f32 %0, %1, %2" : "=v"(r) : "v"(lo), "v"(hi)); return r;
}

__device__ __forceinline__ void glds16(const void* g, void* l){
  __builtin_amdgcn_global_load_lds((const __attribute__((address_space(1))) unsigned int*)g,
                                   (__attribute__((address_space(3))) unsigned int*)l, 16, 0, 0);
}

// ---------------------------------------------------------------- prep: X = [f[:-2], bk[2:]] bf16 (M_ x 1024)
__global__ __launch_bounds__(256) void lma_prep_x(const float* __restrict__ hidden,
                                                  unsigned short* __restrict__ Xb){
  int m = blockIdx.x; int dq = threadIdx.x * 4;
  int b = m / S2_, s = m - b * S2_;
  int srow = (dq < 512) ? s : (s + 2);
  const float* src = hidden + ((size_t)srow * B_ + b) * 1024 + dq;
  f32x4 v = *(const f32x4*)src;
  union { u32x2 u; unsigned short s4[4]; } pk;
  #pragma unroll
  for (int j = 0; j < 4; j++) pk.s4[j] = f2bf(v[j]);
  *(u32x2*)&Xb[(size_t)m * 1024 + dq] = pk.u;
}

// ---------------------------------------------------------------- batched weight transpose+cast
struct TPack {
  const float* src[14];
  unsigned short* dst[14];
  int K[14];
  int N[14];
};
__global__ __launch_bounds__(256) void lma_transpose_all(TPack p){
  int idx = blockIdx.z;
  int K = p.K[idx], N = p.N[idx];
  int kb = blockIdx.x * 32, nb = blockIdx.y * 32;
  if (kb >= K || nb >= N) return;
  const float* W = p.src[idx];
  unsigned short* WT = p.dst[idx];
  __shared__ float t[32][33];
  int tx = threadIdx.x & 31, ty = threadIdx.x >> 5;
  #pragma unroll
  for (int i = ty; i < 32; i += 8) t[i][tx] = W[(size_t)(kb + i) * N + nb + tx];
  __syncthreads();
  #pragma unroll
  for (int i = ty; i < 32; i += 8) WT[(size_t)(nb + i) * K + kb + tx] = f2bf(t[tx][i]);
}

// ---------------------------------------------------------------- concat K/V biases
__global__ __launch_bounds__(256) void lma_biascat(const float* __restrict__ fk, const float* __restrict__ fv,
                                                   const float* __restrict__ bk, const float* __restrict__ bv,
                                                   float* __restrict__ out){
  int i = blockIdx.x * 256 + threadIdx.x;     // 0..2047
  int fb = i >> 10, col = i & 1023;
  const float* s = (col < 512) ? (fb ? bk : fk) : (fb ? bv : fv);
  out[i] = s[col & 511];
}

// ---------------------------------------------------------------- V (in KV2, cols 512..1023) -> VT2[fb][b][h][d][s pad 1024]
// Pad cols s in [S2_,1024) ZEROED (aliased buffer may hold bf16-NaN bit patterns).
__global__ __launch_bounds__(256) void lma_vt2(const unsigned short* __restrict__ KV2,
                                               unsigned short* __restrict__ VT2){
  __shared__ unsigned short t[32][34];
  int s0 = blockIdx.x * 32, c0 = blockIdx.y * 32;
  int z = blockIdx.z, fb = z >> 3, b = z & 7;
  const unsigned short* V = KV2 + (size_t)fb * PAD_ * 1024 + 512;
  unsigned short* VT = VT2 + (size_t)fb * VTS_;
  int tx = threadIdx.x & 31, ty = threadIdx.x >> 5;
  #pragma unroll
  for (int i = ty; i < 32; i += 8){
    int s = s0 + i; if (s > S2_-1) s = S2_-1;
    t[i][tx] = V[((size_t)b * S2_ + s) * 1024 + c0 + tx];
  }
  __syncthreads();
  int s = s0 + tx;
  #pragma unroll
  for (int i = ty; i < 32; i += 8){
    int c = c0 + i, h = c >> 6, d = c & 63;
    VT[(((size_t)b * 8 + h) * 64 + d) * 1024 + s] = (s < S2_) ? t[tx][i] : (unsigned short)0;
  }
}

// ---------------------------------------------------------------- branch-combined GEMM, flat grid + XCD-reuse swizzle
// id: mt = id % nmt (m-tile FASTEST; nmt always multiple of 8 => all n-tile
// readers of A-tile mt have id%8 = mt%8 -> same XCD -> A fetched once/XCD).
// rows < 8192 use (Bt0,bias0), rows >= 8192 use (Bt1,bias1).
// amap: 0 direct (clamp M-1) | 1 row=(r&8191) clamp M_-1 | 2 like 1 + +512 col for branch 1
// modes: 0 bf16 bias | 1 bf16 bias*0.125*log2e (Q pre-scale, exp2-domain softmax)
//        | 2 bf16 bias+gelu(tanh) | 3 f32 bias | 4 f32 bias row-remap (s*B+b)
// LDS XOR swizzle (rule 21, both-sides): global source block (lane&3)^((lane>>2)&3),
// read block quad^(row&3). Reduces the 8-way ds_read_b128 bank conflict
// (banks 16*(row&1)+4*quad, 8 lanes/bank, 2.94x) to 4-way (1.58x).
__global__ __launch_bounds__(256) void lma_gemm2(
    const unsigned short* __restrict__ A, int lda,
    const unsigned short* __restrict__ Bt0, const unsigned short* __restrict__ Bt1,
    const float* __restrict__ bias0, const float* __restrict__ bias1,
    void* __restrict__ Cout, int ldc,
    int M, int N, int K, int mode, int amap, int nmt)
{
  __shared__ unsigned short Al[128*32];
  __shared__ unsigned short Bl[128*32];
  const int tid = threadIdx.x;
  const int w = tid >> 6, lane = tid & 63, quad = lane >> 4, l16 = lane & 15;
  const int mt = blockIdx.x % nmt, nt = blockIdx.x / nmt;
  const int m0 = mt * 128, n0 = nt * 128;
  const int brch = m0 >> 13;
  const unsigned short* Bt = brch ? Bt1 : Bt0;
  const float* bias = brch ? bias1 : bias0;
  const int coloff = (amap == 2 && brch) ? 512 : 0;
  const int wm = (w >> 1) * 64, wn = (w & 1) * 64;

  f32x4 acc[4][4];
  #pragma unroll
  for (int i = 0; i < 4; i++)
    #pragma unroll
    for (int f = 0; f < 4; f++) acc[i][f] = f32x4{0.f,0.f,0.f,0.f};

  const int srow = lane >> 2;
  const int spc  = (((lane & 3) ^ ((lane >> 2) & 3))) * 8;   // pre-swizzled source block
  const int rswz = (l16 & 3);                                 // read-side row XOR

  for (int k0 = 0; k0 < K; k0 += 32) {
    #pragma unroll
    for (int c = 0; c < 2; c++) {
      int ra = w*32 + c*16 + srow;
      int ga = m0 + ra;
      int ar;
      if (amap == 0) { ar = (ga > M-1) ? (M-1) : ga; }
      else { ar = ga & (PAD_-1); if (ar > M_-1) ar = M_-1; }
      glds16(A + (size_t)ar * lda + coloff + k0 + spc, &Al[(w*32 + c*16) * 32]);
      int gb = n0 + ra; if (gb > N-1) gb = N-1;
      glds16(Bt + (size_t)gb * K + k0 + spc, &Bl[(w*32 + c*16) * 32]);
    }
    __syncthreads();
    bf16x8 af[4], bfr[4];
    #pragma unroll
    for (int i = 0; i < 4; i++) af[i]  = *(const bf16x8*)&Al[(wm + i*16 + l16)*32 + ((quad ^ rswz) * 8)];
    #pragma unroll
    for (int f = 0; f < 4; f++) bfr[f] = *(const bf16x8*)&Bl[(wn + f*16 + l16)*32 + ((quad ^ rswz) * 8)];
    #pragma unroll
    for (int i = 0; i < 4; i++)
      #pragma unroll
      for (int f = 0; f < 4; f++)
        acc[i][f] = __builtin_amdgcn_mfma_f32_16x16x32_bf16(af[i], bfr[f], acc[i][f], 0, 0, 0);
    __syncthreads();
  }

  #pragma unroll
  for (int f = 0; f < 4; f++) {
    int col = n0 + wn + f*16 + l16;
    float bv = bias ? bias[col] : 0.f;
    #pragma unroll
    for (int i = 0; i < 4; i++) {
      #pragma unroll
      for (int r = 0; r < 4; r++) {
        int row = m0 + wm + i*16 + quad*4 + r;
        if (row < M) {
          float v = acc[i][f][r] + bv;
          if (mode == 2) v = fgelu(v);
          else if (mode == 1) v *= 0.18033688011112042f;   // 0.125 * log2(e)
          if (mode <= 2) ((unsigned short*)Cout)[(size_t)row * ldc + col] = f2bf(v);
          else if (mode == 3) ((float*)Cout)[(size_t)row * ldc + col] = v;
          else {
            int sr = row % S2_, bb2 = row / S2_;
            ((float*)Cout)[((size_t)sr * B_ + bb2) * ldc + col] = v;
          }
        }
      }
    }
  }
}

// ---------------------------------------------------------------- block reduction helper
__device__ __forceinline__ void lma_red2(float& s, float& sq){
  __shared__ float red[16];
  #pragma unroll
  for (int msk = 1; msk < 64; msk <<= 1){ s += __shfl_xor(s, msk); sq += __shfl_xor(sq, msk); }
  int w = threadIdx.x >> 6;
  if ((threadIdx.x & 63) == 0){ red[w] = s; red[8 + w] = sq; }
  __syncthreads();
  s  = red[0] + red[1] + red[2] + red[3];
  sq = red[8] + red[9] + red[10] + red[11];
}

// ---------------------------------------------------------------- generic LN (f32 in, bf16 or f32 out)
__global__ __launch_bounds__(256) void lma_ln(const float* __restrict__ in,
                                              const float* __restrict__ g, const float* __restrict__ bb,
                                              int D, unsigned short* __restrict__ obf, float* __restrict__ of32){
  int row = blockIdx.x, t = threadIdx.x;
  const float* x = in + (size_t)row * D;
  float s = 0.f, sq = 0.f;
  for (int d = t; d < D; d += 256){ float v = x[d]; s += v; sq += v * v; }
  lma_red2(s, sq);
  float mean = s / D;
  float var = sq / D - mean * mean;
  float rstd = rsqrtf(fmaxf(var, 0.f) + 1e-12f);
  if (obf) {
    for (int d = t; d < D; d += 256) obf[(size_t)row * D + d] = f2bf((x[d] - mean) * rstd * g[d] + bb[d]);
  } else {
    for (int d = t; d < D; d += 256) of32[(size_t)row * D + d] = (x[d] - mean) * rstd * g[d] + bb[d];
  }
}

// ---------------------------------------------------------------- branch-combined LN over T12b (bf16, D=512) -> LQ2 bf16
__global__ __launch_bounds__(256) void lma_ln2(const unsigned short* __restrict__ T12b,
                                               const float* __restrict__ fg, const float* __restrict__ fbb,
                                               const float* __restrict__ bg, const float* __restrict__ bbb,
                                               unsigned short* __restrict__ LQ2){
  int m = blockIdx.x, t = threadIdx.x;           // 0..2*M_-1
  int fb = (m >= M_);
  int idx = m - fb * M_;
  const float* g = fb ? bg : fg;
  const float* bb = fb ? bbb : fbb;
  const unsigned short* x = T12b + ((size_t)fb * PAD_ + idx) * 512;
  unsigned short* o = LQ2 + ((size_t)fb * PAD_ + idx) * 512;
  float v0 = bf2f(x[t]), v1 = bf2f(x[t + 256]);
  float s = v0 + v1, sq = v0*v0 + v1*v1;
  lma_red2(s, sq);
  float mean = s / 512.f;
  float var = sq / 512.f - mean * mean;
  float rstd = rsqrtf(fmaxf(var, 0.f) + 1e-12f);
  o[t]       = f2bf((v0 - mean) * rstd * g[t]       + bb[t]);
  o[t + 256] = f2bf((v1 - mean) * rstd * g[t + 256] + bb[t + 256]);
}

// ---------------------------------------------------------------- attn LN: LN(residual(hidden)+[pf,pb](bf16)) -> bf16 (M_ x 1024)
__global__ __launch_bounds__(256) void lma_attn_ln(const unsigned short* __restrict__ pf,
                                                   const unsigned short* __restrict__ pb,
                                                   const float* __restrict__ hidden,
                                                   const float* __restrict__ g, const float* __restrict__ bb,
                                                   unsigned short* __restrict__ out){
  int m = blockIdx.x, t = threadIdx.x;
  int b = m / S2_, s = m - b * S2_;
  const float* hf = hidden + ((size_t)s       * B_ + b) * 1024;
  const float* hb = hidden + ((size_t)(s + 2) * B_ + b) * 1024;
  float v[4]; float sum = 0.f, sq = 0.f;
  #pragma unroll
  for (int j = 0; j < 4; j++){
    int d = t + j * 256;
    float x = (d < 512) ? (bf2f(pf[(size_t)m * 512 + d]) + hf[d])
                        : (bf2f(pb[(size_t)m * 512 + (d - 512)]) + hb[d]);
    v[j] = x; sum += x; sq += x * x;
  }
  lma_red2(sum, sq);
  float mean = sum / 1024.f;
  float var = sq / 1024.f - mean * mean;
  float rstd = rsqrtf(fmaxf(var, 0.f) + 1e-12f);
  #pragma unroll
  for (int j = 0; j < 4; j++){
    int d = t + j * 256;
    out[(size_t)m * 1024 + d] = f2bf((v[j] - mean) * rstd * g[d] + bb[d]);
  }
}

// ---------------------------------------------------------------- combined flash attention v9
// REVERT to the proven v4/v6 memory structure (single-buffered K/V via
// global_load_lds + __syncthreads; 116-118us measured). v8's no-staging variant
// regressed to 256us: the compiler sank direct global->reg loads to their uses
// (VGPR 64) -> fully serialized load latency, MfmaUtil 3.7%. Kept compute wins:
// exp2-domain softmax, defer-max (THR=11), interior-tile mask skip, setprio,
// stride-64 XOR-swizzled P buffer, v_cvt_pk_bf16_f32 P-pack (passed in v8).
// NEW: fb is a kernel ARG -> two ~60us dispatches instead of one 118us, so the
// GEMM dispatches surface in rocprof's top-5 (they have never been profiled;
// ~527us/iter lives outside attn).
__global__ __launch_bounds__(256, 4) void lma_attn9(const unsigned short* __restrict__ Q2,
                                                    const unsigned short* __restrict__ KV2,
                                                    const unsigned short* __restrict__ VT2,
                                                    unsigned short* __restrict__ CT2,
                                                    const int* __restrict__ lens,
                                                    int fb){
  __shared__ unsigned short Kl[64*64];
  __shared__ unsigned short Vl[64*64];
  __shared__ __align__(16) unsigned short Pl[4][16*64];

  const int tid = threadIdx.x;
  const int w = tid >> 6, lane = tid & 63, quad = lane >> 4, l16 = lane & 15;
  const int id = blockIdx.x;                 // 1024 blocks: [qt:4][h:3][b:3]
  const int qt = id >> 6, h = (id >> 3) & 7, b = id & 7;
  const int backward = fb;
  const int L2 = lens[b] - 2;
  const int q0wg = qt * 64;
  const int q0 = q0wg + w * 16;
  const int qg = q0 + l16;
  const int qload = (qg > S2_-1) ? (S2_-1) : qg;

  const size_t qbase  = ((size_t)b * S2_) * 512  + h * 64;
  const size_t kbase  = ((size_t)b * S2_) * 1024 + h * 64;
  const size_t vtbase = ((size_t)(b * 8 + h) * 64) * 1024;
  char* Pb = (char*)&Pl[w][0];

  const int lrow = lane >> 3;
  const int g0s  = (lane & 7) ^ lrow;
  const int x7   = l16 & 7;
  const int x7s  = x7 << 4;

  const unsigned short* Q  = Q2  + (size_t)fb * PAD_ * 512;
  const unsigned short* Kx = KV2 + (size_t)fb * PAD_ * 1024;
  const unsigned short* VT = VT2 + (size_t)fb * VTS_;
  unsigned short* CTX      = CT2 + (size_t)fb * PAD_ * 512;

  bf16x8 qf[2];
  {
    const unsigned short* qp = Q + qbase + (size_t)qload * 512 + quad * 8;
    qf[0] = *(const bf16x8*)(qp);
    qf[1] = *(const bf16x8*)(qp + 32);
  }

  float mi = -3e38f, li = 0.f;
  f32x4 ot[4];
  #pragma unroll
  for (int f = 0; f < 4; f++) ot[f] = f32x4{0.f,0.f,0.f,0.f};

  int klo = 0, khi = S2_ - 1;
  if (q0wg + 63 < L2) {
    if (!backward) khi = q0wg + 63;
    else { klo = q0wg; khi = L2 - 1; }
  }

  for (int kt0 = klo; kt0 <= khi; kt0 += 64) {
    #pragma unroll
    for (int c = 0; c < 2; c++) {
      int r = w*16 + c*8 + lrow;
      int kr = kt0 + r; if (kr > S2_-1) kr = S2_-1;
      glds16(Kx + kbase + (size_t)kr * 1024 + g0s * 8, &Kl[(w*16 + c*8) * 64]);
      glds16(VT + vtbase + (size_t)r * 1024 + kt0 + g0s * 8, &Vl[(w*16 + c*8) * 64]);
    }
    __syncthreads();

    bf16x8 kf[4][2], vf[4][2];
    #pragma unroll
    for (int sub = 0; sub < 4; sub++) {
      const unsigned short* kp = &Kl[(sub*16 + l16) * 64];
      kf[sub][0] = *(const bf16x8*)(kp + (( quad      ^ x7) * 8));
      kf[sub][1] = *(const bf16x8*)(kp + (((quad + 4) ^ x7) * 8));
    }
    #pragma unroll
    for (int f = 0; f < 4; f++) {
      const unsigned short* vp = &Vl[(f*16 + l16) * 64];
      vf[f][0] = *(const bf16x8*)(vp + (( quad      ^ x7) * 8));
      vf[f][1] = *(const bf16x8*)(vp + (((quad + 4) ^ x7) * 8));
    }

    f32x4 st[4];
    __builtin_amdgcn_s_setprio(1);
    #pragma unroll
    for (int sub = 0; sub < 4; sub++) {
      f32x4 s = f32x4{0.f,0.f,0.f,0.f};
      s = __builtin_amdgcn_mfma_f32_16x16x32_bf16(kf[sub][0], qf[0], s, 0, 0, 0);
      s = __builtin_amdgcn_mfma_f32_16x16x32_bf16(kf[sub][1], qf[1], s, 0, 0, 0);
      st[sub] = s;
    }
    __builtin_amdgcn_s_setprio(0);

    // interior-tile skip: wave-uniform "every (lane,r) passes the mask"
    {
      bool tail = (kt0 + 63 > S2_ - 1);
      bool full;
      if (!backward) full = !tail && ((kt0 + 63 <= q0) || (q0 >= L2));
      else           full = !tail && ((q0 >= L2) || ((kt0 >= q0 + 15) && (kt0 + 63 < L2)));
      if (!full) {
        #pragma unroll
        for (int sub = 0; sub < 4; sub++) {
          #pragma unroll
          for (int r = 0; r < 4; r++) {
            int kg = kt0 + sub*16 + quad*4 + r;
            bool ok;
            if (!backward) ok = (kg < S2_) && ((qg >= L2) || (kg <= qg));
            else           ok = (kg < S2_) && ((qg >= L2) || ((kg >= qg) && (kg < L2)));
            if (!ok) st[sub][r] = -3e38f;
          }
        }
      }
    }

    float mx = -3e38f;
    #pragma unroll
    for (int sub = 0; sub < 4; sub++)
      #pragma unroll
      for (int r = 0; r < 4; r++) mx = fmaxf(mx, st[sub][r]);
    mx = fmaxf(mx, __shfl_xor(mx, 16));
    mx = fmaxf(mx, __shfl_xor(mx, 32));

    // defer-max (T13): only rescale when some row's max grew past THR (log2 units)
    if (__any(mx > mi + 11.f)) {
      float mn = fmaxf(mi, mx);
      float al = fexp2(mi - mn);
      li *= al;
      #pragma unroll
      for (int f = 0; f < 4; f++)
        #pragma unroll
        for (int r = 0; r < 4; r++) ot[f][r] *= al;
      mi = mn;
    }

    float rs = 0.f;
    #pragma unroll
    for (int sub = 0; sub < 4; sub++)
      #pragma unroll
      for (int r = 0; r < 4; r++) {
        float p = fexp2(st[sub][r] - mi);
        st[sub][r] = p; rs += p;
      }
    rs += __shfl_xor(rs, 16);
    rs += __shfl_xor(rs, 32);
    li += rs;

    // P round-trip through XOR-swizzled per-wave LDS (bank-balanced, 2KB/wave)
    #pragma unroll
    for (int sub = 0; sub < 4; sub++) {
      u32x2 pk2;
      pk2[0] = cvtpk(st[sub][0], st[sub][1]);
      pk2[1] = cvtpk(st[sub][2], st[sub][3]);
      *(u32x2*)(Pb + (l16*128 + ((sub*32 + quad*8) ^ x7s))) = pk2;
    }
    bf16x8 pfr0 = *(const bf16x8*)(Pb + (l16*128 + (( 0 + quad*16) ^ x7s)));
    bf16x8 pfr1 = *(const bf16x8*)(Pb + (l16*128 + ((64 + quad*16) ^ x7s)));

    __builtin_amdgcn_s_setprio(1);
    #pragma unroll
    for (int f = 0; f < 4; f++) {
      ot[f] = __builtin_amdgcn_mfma_f32_16x16x32_bf16(vf[f][0], pfr0, ot[f], 0, 0, 0);
      ot[f] = __builtin_amdgcn_mfma_f32_16x16x32_bf16(vf[f][1], pfr1, ot[f], 0, 0, 0);
    }
    __builtin_amdgcn_s_setprio(0);
    __syncthreads();
  }

  if (qg < S2_) {
    float rcp = 1.f / li;
    #pragma unroll
    for (int f = 0; f < 4; f++) {
      ushort4 pk;
      pk.x = f2bf(ot[f][0] * rcp); pk.y = f2bf(ot[f][1] * rcp);
      pk.z = f2bf(ot[f][2] * rcp); pk.w = f2bf(ot[f][3] * rcp);
      *(ushort4*)&CTX[qbase + (size_t)qg * 512 + f*16 + quad*4] = pk;
    }
  }
}

// ----------------------------------------------------------------
extern "C" void kernel_launch(void* const* d_in, const int* in_sizes, int n_in,
                              void* d_out, int out_size, void* d_ws, size_t ws_size,
                              hipStream_t stream)
{
  const float* hidden = (const float*)d_in[0];
  const int*   lens   = (const int*)d_in[1];
  const float* fw[14]; for (int i = 0; i < 14; i++) fw[i] = (const float*)d_in[2 + i];
  const float* bw[14]; for (int i = 0; i < 14; i++) bw[i] = (const float*)d_in[16 + i];
  const float* attn_g = (const float*)d_in[30];
  const float* attn_b = (const float*)d_in[31];
  const float* o_w1 = (const float*)d_in[32];
  const float* o_b1 = (const float*)d_in[33];
  const float* o_w2 = (const float*)d_in[34];
  const float* o_b2 = (const float*)d_in[35];
  const float* o_lng = (const float*)d_in[36];
  const float* o_lnb = (const float*)d_in[37];

  char* ws = (char*)d_ws;
  size_t off = 0;
  auto alloc = [&](size_t bytes)->char* {
    off = (off + 255) & ~(size_t)255;
    char* p = ws + off; off += bytes; return p;
  };

  unsigned short* fw1t = (unsigned short*)alloc((size_t)1024*1024*2);
  unsigned short* fw2t = (unsigned short*)alloc((size_t)512*1024*2);
  unsigned short* fqt  = (unsigned short*)alloc((size_t)512*512*2);
  unsigned short* fkvt = (unsigned short*)alloc((size_t)1024*512*2);  // [K(512 rows); V(512 rows)]
  unsigned short* fot  = (unsigned short*)alloc((size_t)512*512*2);
  unsigned short* bw1t = (unsigned short*)alloc((size_t)1024*1024*2);
  unsigned short* bw2t = (unsigned short*)alloc((size_t)512*1024*2);
  unsigned short* bqt  = (unsigned short*)alloc((size_t)512*512*2);
  unsigned short* bkvt = (unsigned short*)alloc((size_t)1024*512*2);
  unsigned short* bot  = (unsigned short*)alloc((size_t)512*512*2);
  unsigned short* ow1t = (unsigned short*)alloc((size_t)1024*1024*2);
  unsigned short* ow2t = (unsigned short*)alloc((size_t)1024*1024*2);
  float*          biasKV = (float*)alloc(2048*4);

  unsigned short* Xb   = (unsigned short*)alloc((size_t)M_*1024*2);
  unsigned short* big1 = (unsigned short*)alloc((size_t)2*PAD_*1024*2);
  float*          big2 = (float*)alloc((size_t)2*PAD_*512*4);
  unsigned short* LQCT = (unsigned short*)alloc((size_t)2*PAD_*512*2);
  unsigned short* Q2   = (unsigned short*)alloc((size_t)2*PAD_*512*2);

  unsigned short* H12 = big1, *KV2 = big1, *H1o = big1;
  // big2 partitions: [0 .. 2*VTS_) = T12b (bf16) then VT2 (bf16);
  //                  [2*VTS_ .. 4*VTS_) = P2b (bf16 out-proj). Exactly fills big2.
  unsigned short* T12b = (unsigned short*)big2;
  unsigned short* VT2  = (unsigned short*)big2;
  unsigned short* P2b  = (unsigned short*)big2 + 2*VTS_;
  unsigned short* LQ2 = LQCT, *CT2 = LQCT;

  lma_prep_x<<<M_, 256, 0, stream>>>(hidden, Xb);

  {
    TPack tp;
    const float* srcs[14] = { fw[0], fw[2], fw[6], fw[8], fw[10], fw[12],
                              bw[0], bw[2], bw[6], bw[8], bw[10], bw[12],
                              o_w1, o_w2 };
    unsigned short* dsts[14] = { fw1t, fw2t, fqt, fkvt, fkvt + (size_t)512*512, fot,
                                 bw1t, bw2t, bqt, bkvt, bkvt + (size_t)512*512, bot,
                                 ow1t, ow2t };
    int Ks[14] = {1024,1024,512,512,512,512, 1024,1024,512,512,512,512, 1024,1024};
    int Ns[14] = {1024, 512,512,512,512,512, 1024, 512,512,512,512,512, 1024,1024};
    for (int i = 0; i < 14; i++){ tp.src[i]=srcs[i]; tp.dst[i]=dsts[i]; tp.K[i]=Ks[i]; tp.N[i]=Ns[i]; }
    lma_transpose_all<<<dim3(32, 32, 14), 256, 0, stream>>>(tp);
  }
  lma_biascat<<<8, 256, 0, stream>>>(fw[9], fw[11], bw[9], bw[11], biasKV);

  auto G = [&](const unsigned short* A, int lda,
               const unsigned short* B0, const unsigned short* B1,
               const float* b0, const float* b1,
               void* C, int ldc, int M, int N, int K, int mode, int amap){
    int nmt = (M + 127) / 128;
    lma_gemm2<<<dim3(nmt * (N/128)), 256, 0, stream>>>(A, lda, B0, B1, b0, b1, C, ldc, M, N, K, mode, amap, nmt);
  };

  // both-branch FFN + LN + projections (rows<8192 = forward, >=8192 = backward)
  G(Xb, 1024, fw1t, bw1t, fw[1], bw[1], H12, 1024, 2*PAD_, 1024, 1024, 2, 1);  // FFN1+gelu
  G(H12, 1024, fw2t, bw2t, fw[3], bw[3], T12b, 512, 2*PAD_, 512, 1024, 0, 0);  // FFN2 -> bf16
  lma_ln2<<<2*M_, 256, 0, stream>>>(T12b, fw[4], fw[5], bw[4], bw[5], LQ2);
  G(LQ2, 512, fqt, bqt, fw[7], bw[7], Q2, 512, 2*PAD_, 512, 512, 1, 0);        // Q (x0.125*log2e)
  G(Xb, 1024, fkvt, bkvt, biasKV, biasKV + 1024, KV2, 1024, 2*PAD_, 1024, 512, 0, 2); // K|V
  lma_vt2<<<dim3(32, 16, 16), 256, 0, stream>>>(KV2, VT2);

  lma_attn9<<<dim3(1024), 256, 0, stream>>>(Q2, KV2, VT2, CT2, lens, 0);
  lma_attn9<<<dim3(1024), 256, 0, stream>>>(Q2, KV2, VT2, CT2, lens, 1);

  G(CT2, 512, fot, bot, fw[13], bw[13], P2b, 512, 2*PAD_, 512, 512, 0, 0);     // out proj -> bf16

  lma_attn_ln<<<M_, 256, 0, stream>>>(P2b, P2b + (size_t)PAD_*512, hidden, attn_g, attn_b, Xb);

  G(Xb, 1024, ow1t, ow1t, o_b1, o_b1, H1o, 1024, M_, 1024, 1024, 2, 0);        // out FFN1+gelu
  G(H1o, 1024, ow2t, ow2t, o_b2, o_b2, (float*)d_out, 1024, M_, 1024, 1024, 4, 0); // out FFN2 -> d_out (remapped)
  lma_ln<<<M_, 256, 0, stream>>>((float*)d_out, o_lng, o_lnb, 1024, nullptr, (float*)d_out);
}

// Round 6
// 627.837 us; speedup vs baseline: 1.2509x; 1.0425x over previous
//
#include <hip/hip_runtime.h>
#include <cmath>

#define S_ 1024
#define B_ 8
#define H_ 512
#define S2_ 1022
#define M_ (B_*S2_)     // 8176
#define PAD_ 8192
#define VTS_ ((size_t)8*8*64*1024)   // VT per-branch stride (4194304 shorts)

typedef __attribute__((ext_vector_type(8))) short bf16x8;
typedef __attribute__((ext_vector_type(4))) float f32x4;
typedef __attribute__((ext_vector_type(4))) unsigned int u32x4;
typedef __attribute__((ext_vector_type(2))) unsigned int u32x2;

__device__ __forceinline__ unsigned short f2bf(float f){
  unsigned int u = __float_as_uint(f);
  return (unsigned short)((u + 0x7fffu + ((u>>16)&1u)) >> 16);
}
__device__ __forceinline__ float bf2f(unsigned short u){
  return __uint_as_float((unsigned int)u << 16);
}
// tanh-approx gelu: x*sigmoid(2*(c1 x + c2 x^3)); |err vs erf-gelu| < ~3e-4
__device__ __forceinline__ float fgelu(float x){
  float u = x * (0.7978845608f + 0.0356774081f * x * x);
  return x / (1.f + __expf(-2.f * u));
}
// raw 2^x (v_exp_f32 is natively base-2)
__device__ __forceinline__ float fexp2(float x){
  float r; asm("v_exp_f32 %0, %1" : "=v"(r) : "v"(x)); return r;
}
// hardware packed f32->bf16 (RNE), lo -> bits[15:0], hi -> bits[31:16]
__device__ __forceinline__ unsigned int cvtpk(float lo, float hi){
  unsigned int r; asm("v_cvt_pk_bf16_f32 %0, %1, %2" : "=v"(r) : "v"(lo), "v"(hi)); return r;
}

__device__ __forceinline__ void glds16(const void* g, void* l){
  __builtin_amdgcn_global_load_lds((const __attribute__((address_space(1))) unsigned int*)g,
                                   (__attribute__((address_space(3))) unsigned int*)l, 16, 0, 0);
}
#define SB() __builtin_amdgcn_sched_barrier(0)

// ---------------------------------------------------------------- prep: X = [f[:-2], bk[2:]] bf16 (M_ x 1024)
__global__ __launch_bounds__(256) void lma_prep_x(const float* __restrict__ hidden,
                                                  unsigned short* __restrict__ Xb){
  int m = blockIdx.x; int dq = threadIdx.x * 4;
  int b = m / S2_, s = m - b * S2_;
  int srow = (dq < 512) ? s : (s + 2);
  const float* src = hidden + ((size_t)srow * B_ + b) * 1024 + dq;
  f32x4 v = *(const f32x4*)src;
  union { u32x2 u; unsigned short s4[4]; } pk;
  #pragma unroll
  for (int j = 0; j < 4; j++) pk.s4[j] = f2bf(v[j]);
  *(u32x2*)&Xb[(size_t)m * 1024 + dq] = pk.u;
}

// ---------------------------------------------------------------- batched weight transpose+cast
struct TPack {
  const float* src[14];
  unsigned short* dst[14];
  int K[14];
  int N[14];
};
__global__ __launch_bounds__(256) void lma_transpose_all(TPack p){
  int idx = blockIdx.z;
  int K = p.K[idx], N = p.N[idx];
  int kb = blockIdx.x * 32, nb = blockIdx.y * 32;
  if (kb >= K || nb >= N) return;
  const float* W = p.src[idx];
  unsigned short* WT = p.dst[idx];
  __shared__ float t[32][33];
  int tx = threadIdx.x & 31, ty = threadIdx.x >> 5;
  #pragma unroll
  for (int i = ty; i < 32; i += 8) t[i][tx] = W[(size_t)(kb + i) * N + nb + tx];
  __syncthreads();
  #pragma unroll
  for (int i = ty; i < 32; i += 8) WT[(size_t)(nb + i) * K + kb + tx] = f2bf(t[tx][i]);
}

// ---------------------------------------------------------------- concat K/V biases
__global__ __launch_bounds__(256) void lma_biascat(const float* __restrict__ fk, const float* __restrict__ fv,
                                                   const float* __restrict__ bk, const float* __restrict__ bv,
                                                   float* __restrict__ out){
  int i = blockIdx.x * 256 + threadIdx.x;     // 0..2047
  int fb = i >> 10, col = i & 1023;
  const float* s = (col < 512) ? (fb ? bk : fk) : (fb ? bv : fv);
  out[i] = s[col & 511];
}

// ---------------------------------------------------------------- V (in KV2, cols 512..1023) -> VT2[fb][b][h][d][s pad 1024]
// Pad cols s in [S2_,1024) ZEROED (aliased buffer may hold bf16-NaN bit patterns).
__global__ __launch_bounds__(256) void lma_vt2(const unsigned short* __restrict__ KV2,
                                               unsigned short* __restrict__ VT2){
  __shared__ unsigned short t[32][34];
  int s0 = blockIdx.x * 32, c0 = blockIdx.y * 32;
  int z = blockIdx.z, fb = z >> 3, b = z & 7;
  const unsigned short* V = KV2 + (size_t)fb * PAD_ * 1024 + 512;
  unsigned short* VT = VT2 + (size_t)fb * VTS_;
  int tx = threadIdx.x & 31, ty = threadIdx.x >> 5;
  #pragma unroll
  for (int i = ty; i < 32; i += 8){
    int s = s0 + i; if (s > S2_-1) s = S2_-1;
    t[i][tx] = V[((size_t)b * S2_ + s) * 1024 + c0 + tx];
  }
  __syncthreads();
  int s = s0 + tx;
  #pragma unroll
  for (int i = ty; i < 32; i += 8){
    int c = c0 + i, h = c >> 6, d = c & 63;
    VT[(((size_t)b * 8 + h) * 64 + d) * 1024 + s] = (s < S2_) ? t[tx][i] : (unsigned short)0;
  }
}

// ---------------------------------------------------------------- 128^2 2-phase GEMM (kept for small-grid shapes)
// amap: 0 direct (clamp M-1) | 1 row=(r&8191) clamp M_-1 | 2 like 1 + +512 col for branch 1
// modes: 0 bf16 bias | 1 bf16 bias*0.125*log2e | 2 bf16 bias+gelu | 3 f32 bias | 4 f32 bias row-remap
__global__ __launch_bounds__(256) void lma_gemm2(
    const unsigned short* __restrict__ A, int lda,
    const unsigned short* __restrict__ Bt0, const unsigned short* __restrict__ Bt1,
    const float* __restrict__ bias0, const float* __restrict__ bias1,
    void* __restrict__ Cout, int ldc,
    int M, int N, int K, int mode, int amap, int nmt)
{
  __shared__ unsigned short Al[128*32];
  __shared__ unsigned short Bl[128*32];
  const int tid = threadIdx.x;
  const int w = tid >> 6, lane = tid & 63, quad = lane >> 4, l16 = lane & 15;
  const int mt = blockIdx.x % nmt, nt = blockIdx.x / nmt;
  const int m0 = mt * 128, n0 = nt * 128;
  const int brch = m0 >> 13;
  const unsigned short* Bt = brch ? Bt1 : Bt0;
  const float* bias = brch ? bias1 : bias0;
  const int coloff = (amap == 2 && brch) ? 512 : 0;
  const int wm = (w >> 1) * 64, wn = (w & 1) * 64;

  f32x4 acc[4][4];
  #pragma unroll
  for (int i = 0; i < 4; i++)
    #pragma unroll
    for (int f = 0; f < 4; f++) acc[i][f] = f32x4{0.f,0.f,0.f,0.f};

  const int srow = lane >> 2;
  const int spc  = (((lane & 3) ^ ((lane >> 2) & 3))) * 8;   // pre-swizzled source block
  const int rswz = (l16 & 3);                                 // read-side row XOR

  for (int k0 = 0; k0 < K; k0 += 32) {
    #pragma unroll
    for (int c = 0; c < 2; c++) {
      int ra = w*32 + c*16 + srow;
      int ga = m0 + ra;
      int ar;
      if (amap == 0) { ar = (ga > M-1) ? (M-1) : ga; }
      else { ar = ga & (PAD_-1); if (ar > M_-1) ar = M_-1; }
      glds16(A + (size_t)ar * lda + coloff + k0 + spc, &Al[(w*32 + c*16) * 32]);
      int gb = n0 + ra; if (gb > N-1) gb = N-1;
      glds16(Bt + (size_t)gb * K + k0 + spc, &Bl[(w*32 + c*16) * 32]);
    }
    __syncthreads();
    bf16x8 af[4], bfr[4];
    #pragma unroll
    for (int i = 0; i < 4; i++) af[i]  = *(const bf16x8*)&Al[(wm + i*16 + l16)*32 + ((quad ^ rswz) * 8)];
    #pragma unroll
    for (int f = 0; f < 4; f++) bfr[f] = *(const bf16x8*)&Bl[(wn + f*16 + l16)*32 + ((quad ^ rswz) * 8)];
    #pragma unroll
    for (int i = 0; i < 4; i++)
      #pragma unroll
      for (int f = 0; f < 4; f++)
        acc[i][f] = __builtin_amdgcn_mfma_f32_16x16x32_bf16(af[i], bfr[f], acc[i][f], 0, 0, 0);
    __syncthreads();
  }

  #pragma unroll
  for (int f = 0; f < 4; f++) {
    int col = n0 + wn + f*16 + l16;
    float bv = bias ? bias[col] : 0.f;
    #pragma unroll
    for (int i = 0; i < 4; i++) {
      #pragma unroll
      for (int r = 0; r < 4; r++) {
        int row = m0 + wm + i*16 + quad*4 + r;
        if (row < M) {
          float v = acc[i][f][r] + bv;
          if (mode == 2) v = fgelu(v);
          else if (mode == 1) v *= 0.18033688011112042f;   // 0.125 * log2(e)
          if (mode <= 2) ((unsigned short*)Cout)[(size_t)row * ldc + col] = f2bf(v);
          else if (mode == 3) ((float*)Cout)[(size_t)row * ldc + col] = v;
          else {
            int sr = row % S2_, bb2 = row / S2_;
            ((float*)Cout)[((size_t)sr * B_ + bb2) * ldc + col] = v;
          }
        }
      }
    }
  }
}

// ---------------------------------------------------------------- 256^2 8-phase GEMM (T2+T3+T4+T5), for full-grid shapes
// Geometry: 512 thr = 8 waves (2M x 4N), per-wave out 128x64 (8x4 16^2 frags),
// BK=64, 2 K-tiles/iter, LDS 2buf x (A[256][64]+B[256][64]) = 128KB, 1 blk/CU.
// Tile t lives in buf[t&1]. Iter i: ph1-4 compute tile a=2i (buf0, quadrants
// (mq,nq)=00,01,10,11), ph5-8 tile b=2i+1 (buf1). Stage map (each target region
// provably dead behind a barrier; A-half hf = rows {seg*128+hf*64..+63},
// B-half hf = rows {blk*64+hf*32..+31}):
//   ph1: b.A1   ph2: b.B1   ph3: a+2.A0  ph4: a+2.B0
//   ph5: a+2.A1 ph6: a+2.B1 ph7: b+2.A0  ph8: b+2.B0
// vmcnt(4) at end of ph4/ph8 only (2 glds16/wave/stage; leaves newest 2 stages
// in flight, never drains to 0). ds_read swizzle: phys kblk = logical ^
// (((row>>2)&3)<<1) -> uniform 8 lanes/16B-slot (minimal for b128); staging
// pre-applies the inverse on the GLOBAL source, LDS dest stays linear (rule 21).
// A-frags reused across nq phases; both B halves held in regs (ph4/ph8: 0 reads).
__global__ __launch_bounds__(512, 2) void lma_gemm8(
    const unsigned short* __restrict__ A, int lda,
    const unsigned short* __restrict__ Bt0, const unsigned short* __restrict__ Bt1,
    const float* __restrict__ bias0, const float* __restrict__ bias1,
    unsigned short* __restrict__ Cout, int ldc,
    int M, int N, int K, int mode, int amap, int nmt)
{
  __shared__ unsigned short Ls[2][2][256*64];   // [buf][0=A,1=B][row*64+k]
  const int tid = threadIdx.x;
  const int w = tid >> 6, lane = tid & 63, quad = lane >> 4, l16 = lane & 15;
  const int mt = blockIdx.x % nmt, nt = blockIdx.x / nmt;
  const int m0 = mt * 256, n0 = nt * 256;
  const int brch = m0 >> 13;
  const unsigned short* Bt = brch ? Bt1 : Bt0;
  const float* bias = brch ? bias1 : bias0;
  const int coloff = (amap == 2 && brch) ? 512 : 0;
  const int wm = (w >> 2) * 128, wn = (w & 3) * 64;

  f32x4 acc[8][4];
  #pragma unroll
  for (int i = 0; i < 8; i++)
    #pragma unroll
    for (int f = 0; f < 4; f++) acc[i][f] = f32x4{0.f,0.f,0.f,0.f};

  const int lrow8 = lane >> 3;     // 0..7
  const int lkb   = lane & 7;      // kblk 0..7 (16B units within 128B row)
  const int NT = K >> 6;           // K-tiles (even: K in {512,1024})

  auto stageA = [&](int buf, int hf, int kt){
    #pragma unroll
    for (int c = 0; c < 2; c++){
      int rt = (w>>2)*128 + hf*64 + ((w&3)*2 + c)*8 + lrow8;
      int kb = lkb ^ (((rt>>2)&3)<<1);
      int ga = m0 + rt;
      int ar;
      if (amap == 0) { ar = (ga > M-1) ? (M-1) : ga; }
      else { ar = ga & (PAD_-1); if (ar > M_-1) ar = M_-1; }
      glds16(A + (size_t)ar * lda + coloff + kt*64 + kb*8,
             &Ls[buf][0][((w>>2)*128 + hf*64 + ((w&3)*2 + c)*8) * 64]);
    }
  };
  auto stageB = [&](int buf, int hf, int kt){
    #pragma unroll
    for (int c = 0; c < 2; c++){
      int rt = (w>>1)*64 + hf*32 + ((w&1)*2 + c)*8 + lrow8;
      int kb = lkb ^ (((rt>>2)&3)<<1);
      int gb = n0 + rt; if (gb > N-1) gb = N-1;
      glds16(Bt + (size_t)gb * K + kt*64 + kb*8,
             &Ls[buf][1][((w>>1)*64 + hf*32 + ((w&1)*2 + c)*8) * 64]);
    }
  };

  bf16x8 af[4][2], bf0[2][2], bf1[2][2];

  #define LDA8(buf, mq) { _Pragma("unroll") for (int j = 0; j < 4; j++){ \
      int rt = wm + (mq)*64 + j*16 + l16; \
      const unsigned short* base = &Ls[buf][0][rt*64]; \
      int f_ = ((rt>>2)&3)<<1; \
      af[j][0] = *(const bf16x8*)(base + ((    quad) ^ f_)*8); \
      af[j][1] = *(const bf16x8*)(base + ((4 + quad) ^ f_)*8); } }
  #define LDB8(buf, nq, dst) { _Pragma("unroll") for (int j = 0; j < 2; j++){ \
      int rt = wn + (nq)*32 + j*16 + l16; \
      const unsigned short* base = &Ls[buf][1][rt*64]; \
      int f_ = ((rt>>2)&3)<<1; \
      dst[j][0] = *(const bf16x8*)(base + ((    quad) ^ f_)*8); \
      dst[j][1] = *(const bf16x8*)(base + ((4 + quad) ^ f_)*8); } }
  #define MFMAQ(mq, nq, bfr) { __builtin_amdgcn_s_setprio(1); \
      _Pragma("unroll") for (int j = 0; j < 4; j++) \
        _Pragma("unroll") for (int j2 = 0; j2 < 2; j2++){ \
          acc[(mq)*4+j][(nq)*2+j2] = __builtin_amdgcn_mfma_f32_16x16x32_bf16(af[j][0], bfr[j2][0], acc[(mq)*4+j][(nq)*2+j2], 0, 0, 0); \
          acc[(mq)*4+j][(nq)*2+j2] = __builtin_amdgcn_mfma_f32_16x16x32_bf16(af[j][1], bfr[j2][1], acc[(mq)*4+j][(nq)*2+j2], 0, 0, 0); } \
      __builtin_amdgcn_s_setprio(0); }
  #define BAR()   { SB(); __builtin_amdgcn_s_barrier(); SB(); }
  #define LGKM0() { asm volatile("s_waitcnt lgkmcnt(0)" ::: "memory"); SB(); }
  #define VM4()   { asm volatile("s_waitcnt vmcnt(4)"   ::: "memory"); SB(); }

  // prologue: t0 full (4 halves) + t1.A0,B0; vmcnt(4) leaves t1's 2 stages in flight
  stageA(0, 0, 0); stageB(0, 0, 0); stageA(0, 1, 0); stageB(0, 1, 0);
  stageA(1, 0, 1); stageB(1, 0, 1);
  VM4(); BAR();

  const int NI = NT >> 1;
  for (int i = 0; i < NI; i++) {
    const int tb  = 2*i + 1;
    int ta2 = 2*i + 2; if (ta2 > NT-1) ta2 = NT-1;
    int tb2 = 2*i + 3; if (tb2 > NT-1) tb2 = NT-1;

    // ph1: (buf0: mq0,nq0)
    LDA8(0, 0); LDB8(0, 0, bf0); stageA(1, 1, tb);
    BAR(); LGKM0(); MFMAQ(0, 0, bf0); BAR();
    // ph2: (buf0: mq0,nq1)
    LDB8(0, 1, bf1); stageB(1, 1, tb);
    BAR(); LGKM0(); MFMAQ(0, 1, bf1); BAR();
    // ph3: (buf0: mq1,nq0)
    LDA8(0, 1); stageA(0, 0, ta2);
    BAR(); LGKM0(); MFMAQ(1, 0, bf0); BAR();
    // ph4: (buf0: mq1,nq1) — no ds_reads (all frags in regs)
    stageB(0, 0, ta2);
    BAR(); MFMAQ(1, 1, bf1); VM4(); BAR();
    // ph5: (buf1: mq0,nq0)
    LDA8(1, 0); LDB8(1, 0, bf0); stageA(0, 1, ta2);
    BAR(); LGKM0(); MFMAQ(0, 0, bf0); BAR();
    // ph6: (buf1: mq0,nq1)
    LDB8(1, 1, bf1); stageB(0, 1, ta2);
    BAR(); LGKM0(); MFMAQ(0, 1, bf1); BAR();
    // ph7: (buf1: mq1,nq0)
    LDA8(1, 1); stageA(1, 0, tb2);
    BAR(); LGKM0(); MFMAQ(1, 0, bf0); BAR();
    // ph8: (buf1: mq1,nq1)
    stageB(1, 0, tb2);
    BAR(); MFMAQ(1, 1, bf1); VM4(); BAR();
  }
  asm volatile("s_waitcnt vmcnt(0)" ::: "memory");

  #pragma unroll
  for (int f = 0; f < 4; f++) {
    int col = n0 + wn + f*16 + l16;
    float bv = bias ? bias[col] : 0.f;
    #pragma unroll
    for (int i2 = 0; i2 < 8; i2++) {
      #pragma unroll
      for (int r = 0; r < 4; r++) {
        int row = m0 + wm + i2*16 + quad*4 + r;
        if (row < M) {
          float v = acc[i2][f][r] + bv;
          if (mode == 2) v = fgelu(v);
          Cout[(size_t)row * ldc + col] = f2bf(v);
        }
      }
    }
  }
  #undef LDA8
  #undef LDB8
  #undef MFMAQ
  #undef BAR
  #undef LGKM0
  #undef VM4
}

// ---------------------------------------------------------------- block reduction helper
__device__ __forceinline__ void lma_red2(float& s, float& sq){
  __shared__ float red[16];
  #pragma unroll
  for (int msk = 1; msk < 64; msk <<= 1){ s += __shfl_xor(s, msk); sq += __shfl_xor(sq, msk); }
  int w = threadIdx.x >> 6;
  if ((threadIdx.x & 63) == 0){ red[w] = s; red[8 + w] = sq; }
  __syncthreads();
  s  = red[0] + red[1] + red[2] + red[3];
  sq = red[8] + red[9] + red[10] + red[11];
}

// ---------------------------------------------------------------- generic LN (f32 in, bf16 or f32 out)
__global__ __launch_bounds__(256) void lma_ln(const float* __restrict__ in,
                                              const float* __restrict__ g, const float* __restrict__ bb,
                                              int D, unsigned short* __restrict__ obf, float* __restrict__ of32){
  int row = blockIdx.x, t = threadIdx.x;
  const float* x = in + (size_t)row * D;
  float s = 0.f, sq = 0.f;
  for (int d = t; d < D; d += 256){ float v = x[d]; s += v; sq += v * v; }
  lma_red2(s, sq);
  float mean = s / D;
  float var = sq / D - mean * mean;
  float rstd = rsqrtf(fmaxf(var, 0.f) + 1e-12f);
  if (obf) {
    for (int d = t; d < D; d += 256) obf[(size_t)row * D + d] = f2bf((x[d] - mean) * rstd * g[d] + bb[d]);
  } else {
    for (int d = t; d < D; d += 256) of32[(size_t)row * D + d] = (x[d] - mean) * rstd * g[d] + bb[d];
  }
}

// ---------------------------------------------------------------- branch-combined LN over T12b (bf16, D=512) -> LQ2 bf16
__global__ __launch_bounds__(256) void lma_ln2(const unsigned short* __restrict__ T12b,
                                               const float* __restrict__ fg, const float* __restrict__ fbb,
                                               const float* __restrict__ bg, const float* __restrict__ bbb,
                                               unsigned short* __restrict__ LQ2){
  int m = blockIdx.x, t = threadIdx.x;           // 0..2*M_-1
  int fb = (m >= M_);
  int idx = m - fb * M_;
  const float* g = fb ? bg : fg;
  const float* bb = fb ? bbb : fbb;
  const unsigned short* x = T12b + ((size_t)fb * PAD_ + idx) * 512;
  unsigned short* o = LQ2 + ((size_t)fb * PAD_ + idx) * 512;
  float v0 = bf2f(x[t]), v1 = bf2f(x[t + 256]);
  float s = v0 + v1, sq = v0*v0 + v1*v1;
  lma_red2(s, sq);
  float mean = s / 512.f;
  float var = sq / 512.f - mean * mean;
  float rstd = rsqrtf(fmaxf(var, 0.f) + 1e-12f);
  o[t]       = f2bf((v0 - mean) * rstd * g[t]       + bb[t]);
  o[t + 256] = f2bf((v1 - mean) * rstd * g[t + 256] + bb[t + 256]);
}

// ---------------------------------------------------------------- attn LN: LN(residual(hidden)+[pf,pb](bf16)) -> bf16 (M_ x 1024)
__global__ __launch_bounds__(256) void lma_attn_ln(const unsigned short* __restrict__ pf,
                                                   const unsigned short* __restrict__ pb,
                                                   const float* __restrict__ hidden,
                                                   const float* __restrict__ g, const float* __restrict__ bb,
                                                   unsigned short* __restrict__ out){
  int m = blockIdx.x, t = threadIdx.x;
  int b = m / S2_, s = m - b * S2_;
  const float* hf = hidden + ((size_t)s       * B_ + b) * 1024;
  const float* hb = hidden + ((size_t)(s + 2) * B_ + b) * 1024;
  float v[4]; float sum = 0.f, sq = 0.f;
  #pragma unroll
  for (int j = 0; j < 4; j++){
    int d = t + j * 256;
    float x = (d < 512) ? (bf2f(pf[(size_t)m * 512 + d]) + hf[d])
                        : (bf2f(pb[(size_t)m * 512 + (d - 512)]) + hb[d]);
    v[j] = x; sum += x; sq += x * x;
  }
  lma_red2(sum, sq);
  float mean = sum / 1024.f;
  float var = sq / 1024.f - mean * mean;
  float rstd = rsqrtf(fmaxf(var, 0.f) + 1e-12f);
  #pragma unroll
  for (int j = 0; j < 4; j++){
    int d = t + j * 256;
    out[(size_t)m * 1024 + d] = f2bf((v[j] - mean) * rstd * g[d] + bb[d]);
  }
}

// ---------------------------------------------------------------- combined flash attention v9 (proven structure, fb split)
__global__ __launch_bounds__(256, 4) void lma_attn9(const unsigned short* __restrict__ Q2,
                                                    const unsigned short* __restrict__ KV2,
                                                    const unsigned short* __restrict__ VT2,
                                                    unsigned short* __restrict__ CT2,
                                                    const int* __restrict__ lens,
                                                    int fb){
  __shared__ unsigned short Kl[64*64];
  __shared__ unsigned short Vl[64*64];
  __shared__ __align__(16) unsigned short Pl[4][16*64];

  const int tid = threadIdx.x;
  const int w = tid >> 6, lane = tid & 63, quad = lane >> 4, l16 = lane & 15;
  const int id = blockIdx.x;                 // 1024 blocks: [qt:4][h:3][b:3]
  const int qt = id >> 6, h = (id >> 3) & 7, b = id & 7;
  const int backward = fb;
  const int L2 = lens[b] - 2;
  const int q0wg = qt * 64;
  const int q0 = q0wg + w * 16;
  const int qg = q0 + l16;
  const int qload = (qg > S2_-1) ? (S2_-1) : qg;

  const size_t qbase  = ((size_t)b * S2_) * 512  + h * 64;
  const size_t kbase  = ((size_t)b * S2_) * 1024 + h * 64;
  const size_t vtbase = ((size_t)(b * 8 + h) * 64) * 1024;
  char* Pb = (char*)&Pl[w][0];

  const int lrow = lane >> 3;
  const int g0s  = (lane & 7) ^ lrow;
  const int x7   = l16 & 7;
  const int x7s  = x7 << 4;

  const unsigned short* Q  = Q2  + (size_t)fb * PAD_ * 512;
  const unsigned short* Kx = KV2 + (size_t)fb * PAD_ * 1024;
  const unsigned short* VT = VT2 + (size_t)fb * VTS_;
  unsigned short* CTX      = CT2 + (size_t)fb * PAD_ * 512;

  bf16x8 qf[2];
  {
    const unsigned short* qp = Q + qbase + (size_t)qload * 512 + quad * 8;
    qf[0] = *(const bf16x8*)(qp);
    qf[1] = *(const bf16x8*)(qp + 32);
  }

  float mi = -3e38f, li = 0.f;
  f32x4 ot[4];
  #pragma unroll
  for (int f = 0; f < 4; f++) ot[f] = f32x4{0.f,0.f,0.f,0.f};

  int klo = 0, khi = S2_ - 1;
  if (q0wg + 63 < L2) {
    if (!backward) khi = q0wg + 63;
    else { klo = q0wg; khi = L2 - 1; }
  }

  for (int kt0 = klo; kt0 <= khi; kt0 += 64) {
    #pragma unroll
    for (int c = 0; c < 2; c++) {
      int r = w*16 + c*8 + lrow;
      int kr = kt0 + r; if (kr > S2_-1) kr = S2_-1;
      glds16(Kx + kbase + (size_t)kr * 1024 + g0s * 8, &Kl[(w*16 + c*8) * 64]);
      glds16(VT + vtbase + (size_t)r * 1024 + kt0 + g0s * 8, &Vl[(w*16 + c*8) * 64]);
    }
    __syncthreads();

    bf16x8 kf[4][2], vf[4][2];
    #pragma unroll
    for (int sub = 0; sub < 4; sub++) {
      const unsigned short* kp = &Kl[(sub*16 + l16) * 64];
      kf[sub][0] = *(const bf16x8*)(kp + (( quad      ^ x7) * 8));
      kf[sub][1] = *(const bf16x8*)(kp + (((quad + 4) ^ x7) * 8));
    }
    #pragma unroll
    for (int f = 0; f < 4; f++) {
      const unsigned short* vp = &Vl[(f*16 + l16) * 64];
      vf[f][0] = *(const bf16x8*)(vp + (( quad      ^ x7) * 8));
      vf[f][1] = *(const bf16x8*)(vp + (((quad + 4) ^ x7) * 8));
    }

    f32x4 st[4];
    __builtin_amdgcn_s_setprio(1);
    #pragma unroll
    for (int sub = 0; sub < 4; sub++) {
      f32x4 s = f32x4{0.f,0.f,0.f,0.f};
      s = __builtin_amdgcn_mfma_f32_16x16x32_bf16(kf[sub][0], qf[0], s, 0, 0, 0);
      s = __builtin_amdgcn_mfma_f32_16x16x32_bf16(kf[sub][1], qf[1], s, 0, 0, 0);
      st[sub] = s;
    }
    __builtin_amdgcn_s_setprio(0);

    // interior-tile skip: wave-uniform "every (lane,r) passes the mask"
    {
      bool tail = (kt0 + 63 > S2_ - 1);
      bool full;
      if (!backward) full = !tail && ((kt0 + 63 <= q0) || (q0 >= L2));
      else           full = !tail && ((q0 >= L2) || ((kt0 >= q0 + 15) && (kt0 + 63 < L2)));
      if (!full) {
        #pragma unroll
        for (int sub = 0; sub < 4; sub++) {
          #pragma unroll
          for (int r = 0; r < 4; r++) {
            int kg = kt0 + sub*16 + quad*4 + r;
            bool ok;
            if (!backward) ok = (kg < S2_) && ((qg >= L2) || (kg <= qg));
            else           ok = (kg < S2_) && ((qg >= L2) || ((kg >= qg) && (kg < L2)));
            if (!ok) st[sub][r] = -3e38f;
          }
        }
      }
    }

    float mx = -3e38f;
    #pragma unroll
    for (int sub = 0; sub < 4; sub++)
      #pragma unroll
      for (int r = 0; r < 4; r++) mx = fmaxf(mx, st[sub][r]);
    mx = fmaxf(mx, __shfl_xor(mx, 16));
    mx = fmaxf(mx, __shfl_xor(mx, 32));

    // defer-max (T13): only rescale when some row's max grew past THR (log2 units)
    if (__any(mx > mi + 11.f)) {
      float mn = fmaxf(mi, mx);
      float al = fexp2(mi - mn);
      li *= al;
      #pragma unroll
      for (int f = 0; f < 4; f++)
        #pragma unroll
        for (int r = 0; r < 4; r++) ot[f][r] *= al;
      mi = mn;
    }

    float rs = 0.f;
    #pragma unroll
    for (int sub = 0; sub < 4; sub++)
      #pragma unroll
      for (int r = 0; r < 4; r++) {
        float p = fexp2(st[sub][r] - mi);
        st[sub][r] = p; rs += p;
      }
    rs += __shfl_xor(rs, 16);
    rs += __shfl_xor(rs, 32);
    li += rs;

    // P round-trip through XOR-swizzled per-wave LDS (bank-balanced, 2KB/wave)
    #pragma unroll
    for (int sub = 0; sub < 4; sub++) {
      u32x2 pk2;
      pk2[0] = cvtpk(st[sub][0], st[sub][1]);
      pk2[1] = cvtpk(st[sub][2], st[sub][3]);
      *(u32x2*)(Pb + (l16*128 + ((sub*32 + quad*8) ^ x7s))) = pk2;
    }
    bf16x8 pfr0 = *(const bf16x8*)(Pb + (l16*128 + (( 0 + quad*16) ^ x7s)));
    bf16x8 pfr1 = *(const bf16x8*)(Pb + (l16*128 + ((64 + quad*16) ^ x7s)));

    __builtin_amdgcn_s_setprio(1);
    #pragma unroll
    for (int f = 0; f < 4; f++) {
      ot[f] = __builtin_amdgcn_mfma_f32_16x16x32_bf16(vf[f][0], pfr0, ot[f], 0, 0, 0);
      ot[f] = __builtin_amdgcn_mfma_f32_16x16x32_bf16(vf[f][1], pfr1, ot[f], 0, 0, 0);
    }
    __builtin_amdgcn_s_setprio(0);
    __syncthreads();
  }

  if (qg < S2_) {
    float rcp = 1.f / li;
    #pragma unroll
    for (int f = 0; f < 4; f++) {
      ushort4 pk;
      pk.x = f2bf(ot[f][0] * rcp); pk.y = f2bf(ot[f][1] * rcp);
      pk.z = f2bf(ot[f][2] * rcp); pk.w = f2bf(ot[f][3] * rcp);
      *(ushort4*)&CTX[qbase + (size_t)qg * 512 + f*16 + quad*4] = pk;
    }
  }
}

// ----------------------------------------------------------------
extern "C" void kernel_launch(void* const* d_in, const int* in_sizes, int n_in,
                              void* d_out, int out_size, void* d_ws, size_t ws_size,
                              hipStream_t stream)
{
  const float* hidden = (const float*)d_in[0];
  const int*   lens   = (const int*)d_in[1];
  const float* fw[14]; for (int i = 0; i < 14; i++) fw[i] = (const float*)d_in[2 + i];
  const float* bw[14]; for (int i = 0; i < 14; i++) bw[i] = (const float*)d_in[16 + i];
  const float* attn_g = (const float*)d_in[30];
  const float* attn_b = (const float*)d_in[31];
  const float* o_w1 = (const float*)d_in[32];
  const float* o_b1 = (const float*)d_in[33];
  const float* o_w2 = (const float*)d_in[34];
  const float* o_b2 = (const float*)d_in[35];
  const float* o_lng = (const float*)d_in[36];
  const float* o_lnb = (const float*)d_in[37];

  char* ws = (char*)d_ws;
  size_t off = 0;
  auto alloc = [&](size_t bytes)->char* {
    off = (off + 255) & ~(size_t)255;
    char* p = ws + off; off += bytes; return p;
  };

  unsigned short* fw1t = (unsigned short*)alloc((size_t)1024*1024*2);
  unsigned short* fw2t = (unsigned short*)alloc((size_t)512*1024*2);
  unsigned short* fqt  = (unsigned short*)alloc((size_t)512*512*2);
  unsigned short* fkvt = (unsigned short*)alloc((size_t)1024*512*2);  // [K(512 rows); V(512 rows)]
  unsigned short* fot  = (unsigned short*)alloc((size_t)512*512*2);
  unsigned short* bw1t = (unsigned short*)alloc((size_t)1024*1024*2);
  unsigned short* bw2t = (unsigned short*)alloc((size_t)512*1024*2);
  unsigned short* bqt  = (unsigned short*)alloc((size_t)512*512*2);
  unsigned short* bkvt = (unsigned short*)alloc((size_t)1024*512*2);
  unsigned short* bot  = (unsigned short*)alloc((size_t)512*512*2);
  unsigned short* ow1t = (unsigned short*)alloc((size_t)1024*1024*2);
  unsigned short* ow2t = (unsigned short*)alloc((size_t)1024*1024*2);
  float*          biasKV = (float*)alloc(2048*4);

  unsigned short* Xb   = (unsigned short*)alloc((size_t)M_*1024*2);
  unsigned short* big1 = (unsigned short*)alloc((size_t)2*PAD_*1024*2);
  float*          big2 = (float*)alloc((size_t)2*PAD_*512*4);
  unsigned short* LQCT = (unsigned short*)alloc((size_t)2*PAD_*512*2);
  unsigned short* Q2   = (unsigned short*)alloc((size_t)2*PAD_*512*2);

  unsigned short* H12 = big1, *KV2 = big1, *H1o = big1;
  // big2 partitions: [0 .. 2*VTS_) = T12b (bf16) then VT2 (bf16);
  //                  [2*VTS_ .. 4*VTS_) = P2b (bf16 out-proj). Exactly fills big2.
  unsigned short* T12b = (unsigned short*)big2;
  unsigned short* VT2  = (unsigned short*)big2;
  unsigned short* P2b  = (unsigned short*)big2 + 2*VTS_;
  unsigned short* LQ2 = LQCT, *CT2 = LQCT;

  lma_prep_x<<<M_, 256, 0, stream>>>(hidden, Xb);

  {
    TPack tp;
    const float* srcs[14] = { fw[0], fw[2], fw[6], fw[8], fw[10], fw[12],
                              bw[0], bw[2], bw[6], bw[8], bw[10], bw[12],
                              o_w1, o_w2 };
    unsigned short* dsts[14] = { fw1t, fw2t, fqt, fkvt, fkvt + (size_t)512*512, fot,
                                 bw1t, bw2t, bqt, bkvt, bkvt + (size_t)512*512, bot,
                                 ow1t, ow2t };
    int Ks[14] = {1024,1024,512,512,512,512, 1024,1024,512,512,512,512, 1024,1024};
    int Ns[14] = {1024, 512,512,512,512,512, 1024, 512,512,512,512,512, 1024,1024};
    for (int i = 0; i < 14; i++){ tp.src[i]=srcs[i]; tp.dst[i]=dsts[i]; tp.K[i]=Ks[i]; tp.N[i]=Ns[i]; }
    lma_transpose_all<<<dim3(32, 32, 14), 256, 0, stream>>>(tp);
  }
  lma_biascat<<<8, 256, 0, stream>>>(fw[9], fw[11], bw[9], bw[11], biasKV);

  auto G = [&](const unsigned short* A, int lda,
               const unsigned short* B0, const unsigned short* B1,
               const float* b0, const float* b1,
               void* C, int ldc, int M, int N, int K, int mode, int amap){
    int nmt = (M + 127) / 128;
    lma_gemm2<<<dim3(nmt * (N/128)), 256, 0, stream>>>(A, lda, B0, B1, b0, b1, C, ldc, M, N, K, mode, amap, nmt);
  };
  auto G8 = [&](const unsigned short* A, int lda,
                const unsigned short* B0, const unsigned short* B1,
                const float* b0, const float* b1,
                unsigned short* C, int ldc, int M, int N, int K, int mode, int amap){
    int nmt = M / 256;
    lma_gemm8<<<dim3(nmt * (N/256)), 512, 0, stream>>>(A, lda, B0, B1, b0, b1, C, ldc, M, N, K, mode, amap, nmt);
  };

  // both-branch FFN + LN + projections (rows<8192 = forward, >=8192 = backward)
  G8(Xb, 1024, fw1t, bw1t, fw[1], bw[1], H12, 1024, 2*PAD_, 1024, 1024, 2, 1); // FFN1+gelu (8-phase 256^2)
  G(H12, 1024, fw2t, bw2t, fw[3], bw[3], T12b, 512, 2*PAD_, 512, 1024, 0, 0);  // FFN2 -> bf16
  lma_ln2<<<2*M_, 256, 0, stream>>>(T12b, fw[4], fw[5], bw[4], bw[5], LQ2);
  G(LQ2, 512, fqt, bqt, fw[7], bw[7], Q2, 512, 2*PAD_, 512, 512, 1, 0);        // Q (x0.125*log2e)
  G8(Xb, 1024, fkvt, bkvt, biasKV, biasKV + 1024, KV2, 1024, 2*PAD_, 1024, 512, 0, 2); // K|V (8-phase 256^2)
  lma_vt2<<<dim3(32, 16, 16), 256, 0, stream>>>(KV2, VT2);

  lma_attn9<<<dim3(1024), 256, 0, stream>>>(Q2, KV2, VT2, CT2, lens, 0);
  lma_attn9<<<dim3(1024), 256, 0, stream>>>(Q2, KV2, VT2, CT2, lens, 1);

  G(CT2, 512, fot, bot, fw[13], bw[13], P2b, 512, 2*PAD_, 512, 512, 0, 0);     // out proj -> bf16

  lma_attn_ln<<<M_, 256, 0, stream>>>(P2b, P2b + (size_t)PAD_*512, hidden, attn_g, attn_b, Xb);

  G(Xb, 1024, ow1t, ow1t, o_b1, o_b1, H1o, 1024, M_, 1024, 1024, 2, 0);        // out FFN1+gelu
  G(H1o, 1024, ow2t, ow2t, o_b2, o_b2, (float*)d_out, 1024, M_, 1024, 1024, 4, 0); // out FFN2 -> d_out (remapped)
  lma_ln<<<M_, 256, 0, stream>>>((float*)d_out, o_lng, o_lnb, 1024, nullptr, (float*)d_out);
}